// Round 7
// baseline (278.746 us; speedup 1.0000x reference)
//
#include <hip/hip_runtime.h>
#include <hip/hip_bf16.h>

#define SEQN 4096
#define HD 64
#define CCH 512
#define NH 8
#define SC 4            // s-split chunks
#define CHUNK (SEQN / SC)
#define TBK 128         // t per attn block

typedef __attribute__((ext_vector_type(8))) short short8;   // 8 bf16 (4 VGPRs)
typedef __attribute__((ext_vector_type(4))) float f32x4;    // 4 fp32 acc

#define AS1 __attribute__((address_space(1)))
#define AS3 __attribute__((address_space(3)))

#if __has_builtin(__builtin_amdgcn_exp2f)
#define EXP2(x) __builtin_amdgcn_exp2f(x)
#else
#define EXP2(x) exp2f(x)
#endif

// 0.125 * log2(e): fold attention scale AND exp->exp2 conversion into Q
#define QSCALE 0.18033688011112042f

static __device__ __forceinline__ unsigned short f2bf(float f) {
    __hip_bfloat16 h = __float2bfloat16(f);
    return *(unsigned short*)&h;
}
static __device__ __forceinline__ float bf2f(unsigned short u) {
    unsigned int v = ((unsigned int)u) << 16;
    return *(float*)&v;
}
static __device__ __forceinline__ unsigned int fbits(float f) { return *(unsigned int*)&f; }
static __device__ __forceinline__ float hi_f(unsigned int v) {
    unsigned int t = v & 0xFFFF0000u; return *(float*)&t;
}
static __device__ __forceinline__ float lo_f(unsigned int v) {
    unsigned int t = v << 16; return *(float*)&t;
}
static __device__ __forceinline__ unsigned int pkbf(float lo, float hi) {
    return (fbits(hi) & 0xFFFF0000u) | (fbits(lo) >> 16);
}
// half-K fragment: 4 bf16 in first two dwords, zeros above (bit_cast, no union)
static __device__ __forceinline__ short8 half_frag(unsigned int a, unsigned int b) {
    uint4 u; u.x = a; u.y = b; u.z = 0u; u.w = 0u;
    return __builtin_bit_cast(short8, u);
}
static __device__ __forceinline__ void load_lds_16(const unsigned short* g, unsigned short* l) {
    __builtin_amdgcn_global_load_lds((const AS1 void*)g, (AS3 void*)l, 16, 0, 0);
}

// ---------------- prep: GN partial stats (blocks 0..255) + weight cvt (rest)
__global__ __launch_bounds__(256) void prep(const float* __restrict__ x,
                                            float2* __restrict__ partials,
                                            const float* __restrict__ qkv_w,
                                            const float* __restrict__ proj_w,
                                            unsigned short* __restrict__ wq,
                                            unsigned short* __restrict__ wp) {
    const int tid = threadIdx.x;
    if (blockIdx.x < 256) {
        const int b = blockIdx.x;
        const int g = b >> 3;
        const int slice = b & 7;
        const float* xs = x + (size_t)g * 65536 + slice * 8192;
        float s = 0.f, ss = 0.f;
        for (int i = tid; i < 2048; i += 256) {
            float4 v = ((const float4*)xs)[i];
            s  += v.x + v.y + v.z + v.w;
            ss += v.x * v.x + v.y * v.y + v.z * v.z + v.w * v.w;
        }
        for (int off = 32; off; off >>= 1) {
            s  += __shfl_xor(s, off);
            ss += __shfl_xor(ss, off);
        }
        __shared__ float red[8];
        const int wave = tid >> 6;
        const int lane = tid & 63;
        if (lane == 0) { red[wave] = s; red[4 + wave] = ss; }
        __syncthreads();
        if (tid == 0)
            partials[b] = make_float2(red[0] + red[1] + red[2] + red[3],
                                      red[4] + red[5] + red[6] + red[7]);
    } else {
        const int i = (blockIdx.x - 256) * 256 + tid;
        const int NQ = 3 * CCH * CCH / 4;
        float4 f;
        unsigned short* d;
        if (i < NQ) { f = ((const float4*)qkv_w)[i]; d = wq + (size_t)i * 4; }
        else        { f = ((const float4*)proj_w)[i - NQ]; d = wp + (size_t)(i - NQ) * 4; }
        ushort4 o;
        o.x = f2bf(f.x); o.y = f2bf(f.y); o.z = f2bf(f.z); o.w = f2bf(f.w);
        *(ushort4*)d = o;
    }
}

// ---------------- GroupNorm finalize + apply + transpose: x[c][t] -> xnT[t][c] bf16
__global__ __launch_bounds__(256) void gn_norm_t(const float* __restrict__ x,
                                                 const float2* __restrict__ partials,
                                                 const float* __restrict__ w,
                                                 const float* __restrict__ b,
                                                 unsigned short* __restrict__ xnT) {
    __shared__ float tile[64][65];
    __shared__ float gmean[4], grstd[4];
    const int t0 = blockIdx.x * 64;
    const int c0 = blockIdx.y * 64;
    const int tid = threadIdx.x;
    if (tid < 4) {
        int g = (c0 >> 4) + tid;
        float s = 0.f, ss = 0.f;
#pragma unroll
        for (int i = 0; i < 8; i++) {
            float2 p = partials[g * 8 + i];
            s += p.x; ss += p.y;
        }
        float mean = s * (1.f / 65536.f);
        float var  = ss * (1.f / 65536.f) - mean * mean;
        gmean[tid] = mean;
        grstd[tid] = rsqrtf(var + 1e-5f);
    }
    __syncthreads();
    for (int e = tid; e < 1024; e += 256) {
        int r  = e >> 4;
        int t4 = (e & 15) << 2;
        int c = c0 + r;
        float rstd = grstd[r >> 4];
        float sc = w[c] * rstd;
        float sh = b[c] - gmean[r >> 4] * sc;
        float4 v = *(const float4*)(x + (size_t)c * SEQN + t0 + t4);
        tile[r][t4 + 0] = v.x * sc + sh;
        tile[r][t4 + 1] = v.y * sc + sh;
        tile[r][t4 + 2] = v.z * sc + sh;
        tile[r][t4 + 3] = v.w * sc + sh;
    }
    __syncthreads();
    for (int e = tid; e < 1024; e += 256) {
        int t  = e >> 4;
        int c4 = (e & 15) << 2;
        ushort4 o;
        o.x = f2bf(tile[c4 + 0][t]);
        o.y = f2bf(tile[c4 + 1][t]);
        o.z = f2bf(tile[c4 + 2][t]);
        o.w = f2bf(tile[c4 + 3][t]);
        *(ushort4*)(xnT + (size_t)(t0 + t) * CCH + c0 + c4) = o;
    }
}

// ---------------- QKV GEMM: 64x128 tile, BK=64, LDS-staged; fused epilogue
// -> qt/kt [h][t][d] bf16 (Q scaled QSCALE), vv [c][t] bf16.
__global__ __launch_bounds__(256) void gemm_qkv(const unsigned short* __restrict__ Wb,
                                                const unsigned short* __restrict__ xnT,
                                                const float* __restrict__ bias,
                                                unsigned short* __restrict__ qt,
                                                unsigned short* __restrict__ kt,
                                                unsigned short* __restrict__ vv) {
    __shared__ __align__(16) unsigned short Asm[64 * 64];
    __shared__ __align__(16) unsigned short Bsm[128 * 64];
    const int tid = threadIdx.x;
    const int wave = tid >> 6;
    const int lane = tid & 63;
    const int quad = lane >> 4;
    const int l15  = lane & 15;
    const int wm = wave >> 1, wn = wave & 1;
    const int nb = blockIdx.x, mb = blockIdx.y;
    const int sl = lane >> 3, slot = lane & 7;
    const int scol = (slot ^ sl) * 8;

    f32x4 acc[2][4];
#pragma unroll
    for (int mt = 0; mt < 2; mt++)
#pragma unroll
        for (int nt = 0; nt < 4; nt++) acc[mt][nt] = (f32x4){0.f, 0.f, 0.f, 0.f};

    for (int kb = 0; kb < CCH; kb += 64) {
        __syncthreads();
#pragma unroll
        for (int i = 0; i < 2; i++) {
            const int c = wave * 2 + i;
            const int row = c * 8 + sl;
            load_lds_16(Wb + (size_t)(mb * 64 + row) * CCH + kb + scol, &Asm[c * 512]);
        }
#pragma unroll
        for (int i = 0; i < 4; i++) {
            const int c = wave * 4 + i;
            const int row = c * 8 + sl;
            load_lds_16(xnT + (size_t)(nb * 128 + row) * CCH + kb + scol, &Bsm[c * 512]);
        }
        __syncthreads();
#pragma unroll
        for (int kk = 0; kk < 2; kk++) {
            const int so = ((kk * 4 + quad) ^ (l15 & 7)) << 3;
            short8 a[2], b[4];
#pragma unroll
            for (int mt = 0; mt < 2; mt++)
                a[mt] = *(const short8*)(Asm + (wm * 32 + mt * 16 + l15) * 64 + so);
#pragma unroll
            for (int nt = 0; nt < 4; nt++)
                b[nt] = *(const short8*)(Bsm + (wn * 64 + nt * 16 + l15) * 64 + so);
#pragma unroll
            for (int mt = 0; mt < 2; mt++)
#pragma unroll
                for (int nt = 0; nt < 4; nt++)
                    acc[mt][nt] = __builtin_amdgcn_mfma_f32_16x16x32_bf16(a[mt], b[nt], acc[mt][nt], 0, 0, 0);
        }
    }

    const int sel = mb >> 3;                 // 64-row blocks: 0..7=Q, 8..15=K, 16..23=V
#pragma unroll
    for (int mt = 0; mt < 2; mt++) {
        const int m0 = mb * 64 + wm * 32 + mt * 16 + quad * 4;
        float bs[4] = {bias[m0], bias[m0 + 1], bias[m0 + 2], bias[m0 + 3]};
        if (sel < 2) {
            unsigned short* dst = sel ? kt : qt;
            const float mul = sel ? 1.0f : QSCALE;
            const int h  = (m0 >> 6) & 7;
            const int d0 = m0 & 63;
#pragma unroll
            for (int nt = 0; nt < 4; nt++) {
                const int t = nb * 128 + wn * 64 + nt * 16 + l15;
                ushort4 o;
                o.x = f2bf((acc[mt][nt][0] + bs[0]) * mul);
                o.y = f2bf((acc[mt][nt][1] + bs[1]) * mul);
                o.z = f2bf((acc[mt][nt][2] + bs[2]) * mul);
                o.w = f2bf((acc[mt][nt][3] + bs[3]) * mul);
                *(ushort4*)(dst + ((size_t)h * SEQN + t) * HD + d0) = o;
            }
        } else {
            const int c0 = m0 - 1024;
#pragma unroll
            for (int nt = 0; nt < 4; nt++) {
                const int t = nb * 128 + wn * 64 + nt * 16 + l15;
#pragma unroll
                for (int reg = 0; reg < 4; reg++)
                    vv[(size_t)(c0 + reg) * SEQN + t] = f2bf(acc[mt][nt][reg] + bs[reg]);
            }
        }
    }
}

// ---------------- proj GEMM: 64x128 tile, BK=64, LDS-staged; +bias+resid fp32 out
__global__ __launch_bounds__(256) void gemm_proj(const unsigned short* __restrict__ Wb,
                                                 const unsigned short* __restrict__ attnoT,
                                                 const float* __restrict__ bias,
                                                 const float* __restrict__ resid,
                                                 float* __restrict__ out) {
    __shared__ __align__(16) unsigned short Asm[64 * 64];
    __shared__ __align__(16) unsigned short Bsm[128 * 64];
    const int tid = threadIdx.x;
    const int wave = tid >> 6;
    const int lane = tid & 63;
    const int quad = lane >> 4;
    const int l15  = lane & 15;
    const int wm = wave >> 1, wn = wave & 1;
    const int nb = blockIdx.x, mb = blockIdx.y;
    const int sl = lane >> 3, slot = lane & 7;
    const int scol = (slot ^ sl) * 8;

    f32x4 acc[2][4];
#pragma unroll
    for (int mt = 0; mt < 2; mt++)
#pragma unroll
        for (int nt = 0; nt < 4; nt++) acc[mt][nt] = (f32x4){0.f, 0.f, 0.f, 0.f};

    for (int kb = 0; kb < CCH; kb += 64) {
        __syncthreads();
#pragma unroll
        for (int i = 0; i < 2; i++) {
            const int c = wave * 2 + i;
            const int row = c * 8 + sl;
            load_lds_16(Wb + (size_t)(mb * 64 + row) * CCH + kb + scol, &Asm[c * 512]);
        }
#pragma unroll
        for (int i = 0; i < 4; i++) {
            const int c = wave * 4 + i;
            const int row = c * 8 + sl;
            load_lds_16(attnoT + (size_t)(nb * 128 + row) * CCH + kb + scol, &Bsm[c * 512]);
        }
        __syncthreads();
#pragma unroll
        for (int kk = 0; kk < 2; kk++) {
            const int so = ((kk * 4 + quad) ^ (l15 & 7)) << 3;
            short8 a[2], b[4];
#pragma unroll
            for (int mt = 0; mt < 2; mt++)
                a[mt] = *(const short8*)(Asm + (wm * 32 + mt * 16 + l15) * 64 + so);
#pragma unroll
            for (int nt = 0; nt < 4; nt++)
                b[nt] = *(const short8*)(Bsm + (wn * 64 + nt * 16 + l15) * 64 + so);
#pragma unroll
            for (int mt = 0; mt < 2; mt++)
#pragma unroll
                for (int nt = 0; nt < 4; nt++)
                    acc[mt][nt] = __builtin_amdgcn_mfma_f32_16x16x32_bf16(a[mt], b[nt], acc[mt][nt], 0, 0, 0);
        }
    }

#pragma unroll
    for (int mt = 0; mt < 2; mt++) {
        const int m0 = mb * 64 + wm * 32 + mt * 16 + quad * 4;
        float bs[4] = {bias[m0], bias[m0 + 1], bias[m0 + 2], bias[m0 + 3]};
#pragma unroll
        for (int nt = 0; nt < 4; nt++) {
            const int n = nb * 128 + wn * 64 + nt * 16 + l15;
#pragma unroll
            for (int reg = 0; reg < 4; reg++) {
                const size_t off = (size_t)(m0 + reg) * SEQN + n;
                out[off] = acc[mt][nt][reg] + bs[reg] + resid[off];
            }
        }
    }
}

// ---------------- Flash attention: 128-t blocks, wave owns 32 s x 64 t.
// Static softmax (exp2, scale in Q), P in registers (zero-padded K=16 MFMA),
// dbuf LDS staging with hoisted addresses + running global pointers.
__global__ __launch_bounds__(256, 2) void attn(const unsigned short* __restrict__ qt,
                                               const unsigned short* __restrict__ kt,
                                               const unsigned short* __restrict__ vv,
                                               unsigned short* __restrict__ po,
                                               float2* __restrict__ ml) {
    const int tid  = threadIdx.x;
    const int wave = tid >> 6;
    const int lane = tid & 63;
    const int quad = lane >> 4;
    const int l15  = lane & 15;
    const int ws = wave >> 1;      // s-half owner
    const int wt = wave & 1;       // t-half owner (64 t each)
    const int h  = blockIdx.z;
    const int cb = blockIdx.y;
    const int tb = blockIdx.x * TBK;

    const unsigned short* qh = qt + (size_t)h * SEQN * HD;
    const unsigned short* kh = kt + (size_t)h * SEQN * HD;
    const unsigned short* vh = vv + (size_t)h * HD * SEQN;

    // kv[buf][0..4095] = K tile (64 s x 64 d, swizzled); [4096..8191] = V (64 d x 64 s)
    __shared__ __align__(16) unsigned short kv[2][8192];
    __shared__ float lredm[4][4][16];

    const int sl = lane >> 3, slot = lane & 7;
    const int scol = (slot ^ sl) * 8;
    const int x7 = l15 & 7;

    // hoisted LDS element offsets (within one kv buffer)
    int kaoff[2][2];
#pragma unroll
    for (int sm = 0; sm < 2; sm++)
#pragma unroll
        for (int k = 0; k < 2; k++)
            kaoff[sm][k] = (ws * 32 + sm * 16 + l15) * 64 + (((k * 4 + quad) ^ x7) << 3);
    int vpoff[4][2];
#pragma unroll
    for (int dt = 0; dt < 4; dt++)
#pragma unroll
        for (int sm = 0; sm < 2; sm++)
            vpoff[dt][sm] = 4096 + (dt * 16 + l15) * 64 +
                            (((ws * 4 + sm * 2 + (quad >> 1)) ^ x7) << 3) + ((quad & 1) << 2);

    // Q B-frags persistent: B[k=d][n=t], 4 t-tiles of this wave's 64-t half
    short8 qf[4][2];
#pragma unroll
    for (int nt = 0; nt < 4; nt++) {
        const unsigned short* qp = qh + (size_t)(tb + wt * 64 + nt * 16 + l15) * HD + quad * 8;
        qf[nt][0] = *(const short8*)(qp);
        qf[nt][1] = *(const short8*)(qp + 32);
    }

    f32x4 oacc[4][4];   // [d-tile][t-tile], this wave's s-half partial
#pragma unroll
    for (int dt = 0; dt < 4; dt++)
#pragma unroll
        for (int nt = 0; nt < 4; nt++) oacc[dt][nt] = (f32x4){0.f, 0.f, 0.f, 0.f};
    float lsum[4] = {0.f, 0.f, 0.f, 0.f};

    const int s_beg = cb * CHUNK;
    const int NIT = CHUNK / 64;

    // running global staging pointers (advance by fixed strides each iter)
    const unsigned short* kgp  = kh + (size_t)(s_beg + wave * 16 + sl) * HD + scol;
    const unsigned short* vgp0 = vh + (size_t)(wave * 16 + sl) * SEQN + s_beg + scol;
    const unsigned short* vgp1 = vgp0 + (size_t)8 * SEQN;

    // prologue: stage chunk 0 into buf 0
    load_lds_16(kgp,          &kv[0][(wave * 2 + 0) * 512]);
    load_lds_16(kgp + 8 * HD, &kv[0][(wave * 2 + 1) * 512]);
    load_lds_16(vgp0, &kv[0][4096 + (wave * 2 + 0) * 512]);
    load_lds_16(vgp1, &kv[0][4096 + (wave * 2 + 1) * 512]);
    kgp += 64 * HD; vgp0 += 64; vgp1 += 64;

    auto compute = [&](const unsigned short* ksb) {
        // ---- S^T = K·Q^T over this wave's 32 s-rows, 64 t-cols
        short8 ka[2][2];
#pragma unroll
        for (int sm = 0; sm < 2; sm++) {
            ka[sm][0] = *(const short8*)(ksb + kaoff[sm][0]);
            ka[sm][1] = *(const short8*)(ksb + kaoff[sm][1]);
        }
        short8 pfrag[2][4];
#pragma unroll
        for (int sm = 0; sm < 2; sm++)
#pragma unroll
            for (int nt = 0; nt < 4; nt++) {
                f32x4 z = (f32x4){0.f, 0.f, 0.f, 0.f};
                z = __builtin_amdgcn_mfma_f32_16x16x32_bf16(ka[sm][0], qf[nt][0], z, 0, 0, 0);
                z = __builtin_amdgcn_mfma_f32_16x16x32_bf16(ka[sm][1], qf[nt][1], z, 0, 0, 0);
                float p0 = EXP2(z[0]);
                float p1 = EXP2(z[1]);
                float p2 = EXP2(z[2]);
                float p3 = EXP2(z[3]);
                lsum[nt] += (p0 + p1) + (p2 + p3);
                pfrag[sm][nt] = half_frag(pkbf(p0, p1), pkbf(p2, p3));
            }
        // ---- O^T += V^T·P^T (zero-padded K=16)
#pragma unroll
        for (int dt = 0; dt < 4; dt++)
#pragma unroll
            for (int sm = 0; sm < 2; sm++) {
                uint2 vd = *(const uint2*)(ksb + vpoff[dt][sm]);
                short8 va = half_frag(vd.x, vd.y);
#pragma unroll
                for (int nt = 0; nt < 4; nt++)
                    oacc[dt][nt] = __builtin_amdgcn_mfma_f32_16x16x32_bf16(va, pfrag[sm][nt], oacc[dt][nt], 0, 0, 0);
            }
    };

    for (int it2 = 0; it2 < NIT / 2; it2++) {
        // ---- even iter: compute buf0, stage into buf1
        __syncthreads();
        load_lds_16(kgp,          &kv[1][(wave * 2 + 0) * 512]);
        load_lds_16(kgp + 8 * HD, &kv[1][(wave * 2 + 1) * 512]);
        load_lds_16(vgp0, &kv[1][4096 + (wave * 2 + 0) * 512]);
        load_lds_16(vgp1, &kv[1][4096 + (wave * 2 + 1) * 512]);
        kgp += 64 * HD; vgp0 += 64; vgp1 += 64;
        compute(&kv[0][0]);
        // ---- odd iter: compute buf1, stage into buf0 (except last)
        __syncthreads();
        if (it2 + 1 < NIT / 2) {
            load_lds_16(kgp,          &kv[0][(wave * 2 + 0) * 512]);
            load_lds_16(kgp + 8 * HD, &kv[0][(wave * 2 + 1) * 512]);
            load_lds_16(vgp0, &kv[0][4096 + (wave * 2 + 0) * 512]);
            load_lds_16(vgp1, &kv[0][4096 + (wave * 2 + 1) * 512]);
            kgp += 64 * HD; vgp0 += 64; vgp1 += 64;
        }
        compute(&kv[1][0]);
    }

    // ---- cross-wave (s-half pair) reduction through LDS
    __syncthreads();
    unsigned int* exg = (unsigned int*)&kv[0][0];   // 4 waves x 2 dt x 4 nt x 64 lanes x 2 dw = 16 KB
#pragma unroll
    for (int nt = 0; nt < 4; nt++) {
        lsum[nt] += __shfl_xor(lsum[nt], 16);
        lsum[nt] += __shfl_xor(lsum[nt], 32);
    }
    if (quad == 0) {
#pragma unroll
        for (int nt = 0; nt < 4; nt++) lredm[wave][nt][l15] = lsum[nt];
    }
#pragma unroll
    for (int j = 0; j < 2; j++) {
        const int dt = (ws ^ 1) * 2 + j;      // the d-half I do NOT own
#pragma unroll
        for (int nt = 0; nt < 4; nt++) {
            const int idx = (((wave * 2 + j) * 4 + nt) * 64 + lane) * 2;
            exg[idx]     = pkbf(oacc[dt][nt][0], oacc[dt][nt][1]);
            exg[idx + 1] = pkbf(oacc[dt][nt][2], oacc[dt][nt][3]);
        }
    }
    __syncthreads();
    const int pw = wave ^ 2;                  // partner: other s-half, same t-half
#pragma unroll
    for (int j = 0; j < 2; j++) {
        const int dtm = ws * 2 + j;           // my owned d-tiles
#pragma unroll
        for (int nt = 0; nt < 4; nt++) {
            const float lt = lredm[wave][nt][l15] + lredm[pw][nt][l15];
            const int idx = (((pw * 2 + j) * 4 + nt) * 64 + lane) * 2;
            unsigned int r0 = exg[idx], r1 = exg[idx + 1];
            f32x4 o = oacc[dtm][nt];
            o[0] += lo_f(r0); o[1] += hi_f(r0);
            o[2] += lo_f(r1); o[3] += hi_f(r1);
            const float rl = 1.0f / lt;
            const int t = tb + wt * 64 + nt * 16 + l15;
            ushort4 ov;
            ov.x = f2bf(o[0] * rl); ov.y = f2bf(o[1] * rl);
            ov.z = f2bf(o[2] * rl); ov.w = f2bf(o[3] * rl);
            *(ushort4*)(po + ((size_t)(cb * NH + h) * SEQN + t) * HD + dtm * 16 + quad * 4) = ov;
            if (ws == 0 && quad == 0 && j == 0)
                ml[(size_t)(cb * NH + h) * SEQN + t] = make_float2(0.f, lt);
        }
    }
}

// ---------------- merge s-chunks (weights = per-chunk l) -> attnoT [t][c] bf16
__global__ __launch_bounds__(256) void attn_merge(const unsigned short* __restrict__ po,
                                                  const float2* __restrict__ ml,
                                                  unsigned short* __restrict__ attnoT) {
    const int idx = blockIdx.x * 256 + threadIdx.x;
    const int t  = idx >> 7;
    const int c4 = (idx & 127) << 2;
    const int h  = c4 >> 6;
    const int d  = c4 & 63;

    float a0 = 0.f, a1 = 0.f, a2 = 0.f, a3 = 0.f, denom = 0.f;
#pragma unroll
    for (int cb = 0; cb < SC; cb++) {
        float wgt = ml[(size_t)(cb * NH + h) * SEQN + t].y;
        denom += wgt;
        ushort4 o = *(const ushort4*)(po + ((size_t)(cb * NH + h) * SEQN + t) * HD + d);
        a0 += wgt * bf2f(o.x);
        a1 += wgt * bf2f(o.y);
        a2 += wgt * bf2f(o.z);
        a3 += wgt * bf2f(o.w);
    }
    const float rd = 1.0f / denom;
    ushort4 r;
    r.x = f2bf(a0 * rd); r.y = f2bf(a1 * rd); r.z = f2bf(a2 * rd); r.w = f2bf(a3 * rd);
    *(ushort4*)(attnoT + (size_t)t * CCH + c4) = r;
}

extern "C" void kernel_launch(void* const* d_in, const int* in_sizes, int n_in,
                              void* d_out, int out_size, void* d_ws, size_t ws_size,
                              hipStream_t stream) {
    const float* x      = (const float*)d_in[0];
    const float* gn_w   = (const float*)d_in[1];
    const float* gn_b   = (const float*)d_in[2];
    const float* qkv_w  = (const float*)d_in[3];
    const float* qkv_b  = (const float*)d_in[4];
    const float* proj_w = (const float*)d_in[5];
    const float* proj_b = (const float*)d_in[6];
    float* out = (float*)d_out;

    char* ws = (char*)d_ws;
    float2* partials = (float2*)ws;                                // 2 KB
    unsigned short* xnT   = (unsigned short*)(ws + 2048);          // 4096*512
    unsigned short* wq_bf = xnT + (size_t)SEQN * CCH;              // 1536*512
    unsigned short* wp_bf = wq_bf + (size_t)3 * CCH * CCH;         // 512*512
    unsigned short* qt    = wp_bf + (size_t)CCH * CCH;             // 8*4096*64
    unsigned short* kt    = qt + (size_t)NH * SEQN * HD;
    unsigned short* vv    = kt + (size_t)NH * SEQN * HD;
    unsigned short* po    = vv + (size_t)NH * SEQN * HD;           // SC*8*4096*64
    unsigned short* attnoT = po + (size_t)SC * NH * SEQN * HD;     // 4096*512
    float2* ml = (float2*)(attnoT + (size_t)SEQN * CCH);           // SC*8*4096

    prep<<<256 + (3 * CCH * CCH + CCH * CCH) / 4 / 256, 256, 0, stream>>>(
        x, partials, qkv_w, proj_w, wq_bf, wp_bf);
    gn_norm_t<<<dim3(SEQN / 64, CCH / 64), 256, 0, stream>>>(x, partials, gn_w, gn_b, xnT);
    gemm_qkv<<<dim3(SEQN / 128, 3 * CCH / 64), 256, 0, stream>>>(wq_bf, xnT, qkv_b, qt, kt, vv);
    attn<<<dim3(SEQN / TBK, SC, NH), 256, 0, stream>>>(qt, kt, vv, po, ml);
    attn_merge<<<SEQN * 128 / 256, 256, 0, stream>>>(po, ml, attnoT);
    gemm_proj<<<dim3(SEQN / 128, CCH / 64), 256, 0, stream>>>(wp_bf, attnoT, proj_b, x, out);
}

// Round 8
// 194.909 us; speedup vs baseline: 1.4301x; 1.4301x over previous
//
#include <hip/hip_runtime.h>
#include <hip/hip_bf16.h>

#define SEQN 4096
#define HD 64
#define CCH 512
#define NH 8
#define SC 4            // s-split chunks
#define CHUNK (SEQN / SC)

typedef __attribute__((ext_vector_type(8))) short short8;   // 8 bf16 (4 VGPRs)
typedef __attribute__((ext_vector_type(4))) float f32x4;    // 4 fp32 acc

#define AS1 __attribute__((address_space(1)))
#define AS3 __attribute__((address_space(3)))

#if __has_builtin(__builtin_amdgcn_exp2f)
#define EXP2(x) __builtin_amdgcn_exp2f(x)
#else
#define EXP2(x) exp2f(x)
#endif

// 0.125 * log2(e): fold attention scale AND exp->exp2 conversion into Q
#define QSCALE 0.18033688011112042f

static __device__ __forceinline__ unsigned short f2bf(float f) {
    __hip_bfloat16 h = __float2bfloat16(f);
    return *(unsigned short*)&h;
}
static __device__ __forceinline__ float bf2f(unsigned short u) {
    unsigned int v = ((unsigned int)u) << 16;
    return *(float*)&v;
}
static __device__ __forceinline__ unsigned int fbits(float f) { return *(unsigned int*)&f; }
static __device__ __forceinline__ float hi_f(unsigned int v) {
    unsigned int t = v & 0xFFFF0000u; return *(float*)&t;
}
static __device__ __forceinline__ float lo_f(unsigned int v) {
    unsigned int t = v << 16; return *(float*)&t;
}
static __device__ __forceinline__ unsigned int pkbf(float lo, float hi) {
    return (fbits(hi) & 0xFFFF0000u) | (fbits(lo) >> 16);
}
// full-K fragment from 4 dwords (bit_cast, no union — unions force scratch)
static __device__ __forceinline__ short8 frag4(unsigned int a, unsigned int b,
                                               unsigned int c, unsigned int d) {
    uint4 u; u.x = a; u.y = b; u.z = c; u.w = d;
    return __builtin_bit_cast(short8, u);
}
static __device__ __forceinline__ void load_lds_16(const unsigned short* g, unsigned short* l) {
    __builtin_amdgcn_global_load_lds((const AS1 void*)g, (AS3 void*)l, 16, 0, 0);
}

// ---------------- prep: GN partial stats (blocks 0..255) + weight cvt (rest)
__global__ __launch_bounds__(256) void prep(const float* __restrict__ x,
                                            float2* __restrict__ partials,
                                            const float* __restrict__ qkv_w,
                                            const float* __restrict__ proj_w,
                                            unsigned short* __restrict__ wq,
                                            unsigned short* __restrict__ wp) {
    const int tid = threadIdx.x;
    if (blockIdx.x < 256) {
        const int b = blockIdx.x;
        const int g = b >> 3;
        const int slice = b & 7;
        const float* xs = x + (size_t)g * 65536 + slice * 8192;
        float s = 0.f, ss = 0.f;
        for (int i = tid; i < 2048; i += 256) {
            float4 v = ((const float4*)xs)[i];
            s  += v.x + v.y + v.z + v.w;
            ss += v.x * v.x + v.y * v.y + v.z * v.z + v.w * v.w;
        }
        for (int off = 32; off; off >>= 1) {
            s  += __shfl_xor(s, off);
            ss += __shfl_xor(ss, off);
        }
        __shared__ float red[8];
        const int wave = tid >> 6;
        const int lane = tid & 63;
        if (lane == 0) { red[wave] = s; red[4 + wave] = ss; }
        __syncthreads();
        if (tid == 0)
            partials[b] = make_float2(red[0] + red[1] + red[2] + red[3],
                                      red[4] + red[5] + red[6] + red[7]);
    } else {
        const int i = (blockIdx.x - 256) * 256 + tid;
        const int NQ = 3 * CCH * CCH / 4;
        float4 f;
        unsigned short* d;
        if (i < NQ) { f = ((const float4*)qkv_w)[i]; d = wq + (size_t)i * 4; }
        else        { f = ((const float4*)proj_w)[i - NQ]; d = wp + (size_t)(i - NQ) * 4; }
        ushort4 o;
        o.x = f2bf(f.x); o.y = f2bf(f.y); o.z = f2bf(f.z); o.w = f2bf(f.w);
        *(ushort4*)d = o;
    }
}

// ---------------- GroupNorm finalize + apply + transpose: x[c][t] -> xnT[t][c] bf16
__global__ __launch_bounds__(256) void gn_norm_t(const float* __restrict__ x,
                                                 const float2* __restrict__ partials,
                                                 const float* __restrict__ w,
                                                 const float* __restrict__ b,
                                                 unsigned short* __restrict__ xnT) {
    __shared__ float tile[64][65];
    __shared__ float gmean[4], grstd[4];
    const int t0 = blockIdx.x * 64;
    const int c0 = blockIdx.y * 64;
    const int tid = threadIdx.x;
    if (tid < 4) {
        int g = (c0 >> 4) + tid;
        float s = 0.f, ss = 0.f;
#pragma unroll
        for (int i = 0; i < 8; i++) {
            float2 p = partials[g * 8 + i];
            s += p.x; ss += p.y;
        }
        float mean = s * (1.f / 65536.f);
        float var  = ss * (1.f / 65536.f) - mean * mean;
        gmean[tid] = mean;
        grstd[tid] = rsqrtf(var + 1e-5f);
    }
    __syncthreads();
    for (int e = tid; e < 1024; e += 256) {
        int r  = e >> 4;
        int t4 = (e & 15) << 2;
        int c = c0 + r;
        float rstd = grstd[r >> 4];
        float sc = w[c] * rstd;
        float sh = b[c] - gmean[r >> 4] * sc;
        float4 v = *(const float4*)(x + (size_t)c * SEQN + t0 + t4);
        tile[r][t4 + 0] = v.x * sc + sh;
        tile[r][t4 + 1] = v.y * sc + sh;
        tile[r][t4 + 2] = v.z * sc + sh;
        tile[r][t4 + 3] = v.w * sc + sh;
    }
    __syncthreads();
    for (int e = tid; e < 1024; e += 256) {
        int t  = e >> 4;
        int c4 = (e & 15) << 2;
        ushort4 o;
        o.x = f2bf(tile[c4 + 0][t]);
        o.y = f2bf(tile[c4 + 1][t]);
        o.z = f2bf(tile[c4 + 2][t]);
        o.w = f2bf(tile[c4 + 3][t]);
        *(ushort4*)(xnT + (size_t)(t0 + t) * CCH + c0 + c4) = o;
    }
}

// ---------------- QKV GEMM: 64x128 tile, BK=64, LDS-staged; fused epilogue
// -> qt/kt [h][t][d] bf16 (Q scaled QSCALE), vv [c][t] bf16.
__global__ __launch_bounds__(256) void gemm_qkv(const unsigned short* __restrict__ Wb,
                                                const unsigned short* __restrict__ xnT,
                                                const float* __restrict__ bias,
                                                unsigned short* __restrict__ qt,
                                                unsigned short* __restrict__ kt,
                                                unsigned short* __restrict__ vv) {
    __shared__ __align__(16) unsigned short Asm[64 * 64];
    __shared__ __align__(16) unsigned short Bsm[128 * 64];
    const int tid = threadIdx.x;
    const int wave = tid >> 6;
    const int lane = tid & 63;
    const int quad = lane >> 4;
    const int l15  = lane & 15;
    const int wm = wave >> 1, wn = wave & 1;
    const int nb = blockIdx.x, mb = blockIdx.y;
    const int sl = lane >> 3, slot = lane & 7;
    const int scol = (slot ^ sl) * 8;

    f32x4 acc[2][4];
#pragma unroll
    for (int mt = 0; mt < 2; mt++)
#pragma unroll
        for (int nt = 0; nt < 4; nt++) acc[mt][nt] = (f32x4){0.f, 0.f, 0.f, 0.f};

    for (int kb = 0; kb < CCH; kb += 64) {
        __syncthreads();
#pragma unroll
        for (int i = 0; i < 2; i++) {
            const int c = wave * 2 + i;
            const int row = c * 8 + sl;
            load_lds_16(Wb + (size_t)(mb * 64 + row) * CCH + kb + scol, &Asm[c * 512]);
        }
#pragma unroll
        for (int i = 0; i < 4; i++) {
            const int c = wave * 4 + i;
            const int row = c * 8 + sl;
            load_lds_16(xnT + (size_t)(nb * 128 + row) * CCH + kb + scol, &Bsm[c * 512]);
        }
        __syncthreads();
#pragma unroll
        for (int kk = 0; kk < 2; kk++) {
            const int so = ((kk * 4 + quad) ^ (l15 & 7)) << 3;
            short8 a[2], b[4];
#pragma unroll
            for (int mt = 0; mt < 2; mt++)
                a[mt] = *(const short8*)(Asm + (wm * 32 + mt * 16 + l15) * 64 + so);
#pragma unroll
            for (int nt = 0; nt < 4; nt++)
                b[nt] = *(const short8*)(Bsm + (wn * 64 + nt * 16 + l15) * 64 + so);
#pragma unroll
            for (int mt = 0; mt < 2; mt++)
#pragma unroll
                for (int nt = 0; nt < 4; nt++)
                    acc[mt][nt] = __builtin_amdgcn_mfma_f32_16x16x32_bf16(a[mt], b[nt], acc[mt][nt], 0, 0, 0);
        }
    }

    const int sel = mb >> 3;                 // 64-row blocks: 0..7=Q, 8..15=K, 16..23=V
#pragma unroll
    for (int mt = 0; mt < 2; mt++) {
        const int m0 = mb * 64 + wm * 32 + mt * 16 + quad * 4;
        float bs[4] = {bias[m0], bias[m0 + 1], bias[m0 + 2], bias[m0 + 3]};
        if (sel < 2) {
            unsigned short* dst = sel ? kt : qt;
            const float mul = sel ? 1.0f : QSCALE;
            const int h  = (m0 >> 6) & 7;
            const int d0 = m0 & 63;
#pragma unroll
            for (int nt = 0; nt < 4; nt++) {
                const int t = nb * 128 + wn * 64 + nt * 16 + l15;
                ushort4 o;
                o.x = f2bf((acc[mt][nt][0] + bs[0]) * mul);
                o.y = f2bf((acc[mt][nt][1] + bs[1]) * mul);
                o.z = f2bf((acc[mt][nt][2] + bs[2]) * mul);
                o.w = f2bf((acc[mt][nt][3] + bs[3]) * mul);
                *(ushort4*)(dst + ((size_t)h * SEQN + t) * HD + d0) = o;
            }
        } else {
            const int c0 = m0 - 1024;
#pragma unroll
            for (int nt = 0; nt < 4; nt++) {
                const int t = nb * 128 + wn * 64 + nt * 16 + l15;
#pragma unroll
                for (int reg = 0; reg < 4; reg++)
                    vv[(size_t)(c0 + reg) * SEQN + t] = f2bf(acc[mt][nt][reg] + bs[reg]);
            }
        }
    }
}

// ---------------- proj GEMM: 64x128 tile, BK=64, LDS-staged; +bias+resid fp32 out
__global__ __launch_bounds__(256) void gemm_proj(const unsigned short* __restrict__ Wb,
                                                 const unsigned short* __restrict__ attnoT,
                                                 const float* __restrict__ bias,
                                                 const float* __restrict__ resid,
                                                 float* __restrict__ out) {
    __shared__ __align__(16) unsigned short Asm[64 * 64];
    __shared__ __align__(16) unsigned short Bsm[128 * 64];
    const int tid = threadIdx.x;
    const int wave = tid >> 6;
    const int lane = tid & 63;
    const int quad = lane >> 4;
    const int l15  = lane & 15;
    const int wm = wave >> 1, wn = wave & 1;
    const int nb = blockIdx.x, mb = blockIdx.y;
    const int sl = lane >> 3, slot = lane & 7;
    const int scol = (slot ^ sl) * 8;

    f32x4 acc[2][4];
#pragma unroll
    for (int mt = 0; mt < 2; mt++)
#pragma unroll
        for (int nt = 0; nt < 4; nt++) acc[mt][nt] = (f32x4){0.f, 0.f, 0.f, 0.f};

    for (int kb = 0; kb < CCH; kb += 64) {
        __syncthreads();
#pragma unroll
        for (int i = 0; i < 2; i++) {
            const int c = wave * 2 + i;
            const int row = c * 8 + sl;
            load_lds_16(Wb + (size_t)(mb * 64 + row) * CCH + kb + scol, &Asm[c * 512]);
        }
#pragma unroll
        for (int i = 0; i < 4; i++) {
            const int c = wave * 4 + i;
            const int row = c * 8 + sl;
            load_lds_16(attnoT + (size_t)(nb * 128 + row) * CCH + kb + scol, &Bsm[c * 512]);
        }
        __syncthreads();
#pragma unroll
        for (int kk = 0; kk < 2; kk++) {
            const int so = ((kk * 4 + quad) ^ (l15 & 7)) << 3;
            short8 a[2], b[4];
#pragma unroll
            for (int mt = 0; mt < 2; mt++)
                a[mt] = *(const short8*)(Asm + (wm * 32 + mt * 16 + l15) * 64 + so);
#pragma unroll
            for (int nt = 0; nt < 4; nt++)
                b[nt] = *(const short8*)(Bsm + (wn * 64 + nt * 16 + l15) * 64 + so);
#pragma unroll
            for (int mt = 0; mt < 2; mt++)
#pragma unroll
                for (int nt = 0; nt < 4; nt++)
                    acc[mt][nt] = __builtin_amdgcn_mfma_f32_16x16x32_bf16(a[mt], b[nt], acc[mt][nt], 0, 0, 0);
        }
    }

#pragma unroll
    for (int mt = 0; mt < 2; mt++) {
        const int m0 = mb * 64 + wm * 32 + mt * 16 + quad * 4;
        float bs[4] = {bias[m0], bias[m0 + 1], bias[m0 + 2], bias[m0 + 3]};
#pragma unroll
        for (int nt = 0; nt < 4; nt++) {
            const int n = nb * 128 + wn * 64 + nt * 16 + l15;
#pragma unroll
            for (int reg = 0; reg < 4; reg++) {
                const size_t off = (size_t)(m0 + reg) * SEQN + n;
                out[off] = acc[mt][nt][reg] + bs[reg] + resid[off];
            }
        }
    }
}

// ---------------- Flash attention: 64-t blocks, 2x2 wave grid (32 s x 32 t).
// Static softmax (exp2, scale in Q); P packed in-register into a FULL K=32
// B-fragment (two s-subtiles in disjoint dword pairs) -> 8 PV MFMAs/iter.
// Hoisted LDS offsets, running global pointers, compile-time dbuf unroll.
__global__ __launch_bounds__(256) void attn(const unsigned short* __restrict__ qt,
                                            const unsigned short* __restrict__ kt,
                                            const unsigned short* __restrict__ vv,
                                            unsigned short* __restrict__ po,
                                            float2* __restrict__ ml) {
    const int tid  = threadIdx.x;
    const int wave = tid >> 6;
    const int lane = tid & 63;
    const int quad = lane >> 4;
    const int l15  = lane & 15;
    const int ws = wave >> 1;      // s-half owner (32 s)
    const int wt = wave & 1;       // t-half owner (32 t)
    const int h  = blockIdx.z;
    const int cb = blockIdx.y;
    const int tb = blockIdx.x * 64;

    const unsigned short* qh = qt + (size_t)h * SEQN * HD;
    const unsigned short* kh = kt + (size_t)h * SEQN * HD;
    const unsigned short* vh = vv + (size_t)h * HD * SEQN;

    // kv[buf][0..4095] = K tile (64 s x 64 d, swizzled); [4096..8191] = V (64 d x 64 s)
    __shared__ __align__(16) unsigned short kv[2][8192];
    __shared__ float lredm[4][2][16];

    const int sl = lane >> 3, slot = lane & 7;
    const int scol = (slot ^ sl) * 8;
    const int x7 = l15 & 7;

    // hoisted LDS element offsets
    int kaoff[2][2];
#pragma unroll
    for (int sm = 0; sm < 2; sm++)
#pragma unroll
        for (int k = 0; k < 2; k++)
            kaoff[sm][k] = (ws * 32 + sm * 16 + l15) * 64 + (((k * 4 + quad) ^ x7) << 3);
    int vpoff[4][2];
#pragma unroll
    for (int dt = 0; dt < 4; dt++)
#pragma unroll
        for (int sm = 0; sm < 2; sm++)
            vpoff[dt][sm] = 4096 + (dt * 16 + l15) * 64 +
                            (((ws * 4 + sm * 2 + (quad >> 1)) ^ x7) << 3) + ((quad & 1) << 2);

    // Q B-frags persistent: B[k=d][n=t] for this wave's 2 t-tiles
    short8 qf[2][2];
#pragma unroll
    for (int nt = 0; nt < 2; nt++) {
        const unsigned short* qp = qh + (size_t)(tb + wt * 32 + nt * 16 + l15) * HD + quad * 8;
        qf[nt][0] = *(const short8*)(qp);
        qf[nt][1] = *(const short8*)(qp + 32);
    }

    f32x4 oacc[4][2];   // [d-tile 0..3][t-tile 0..1], this wave's s-half partial
#pragma unroll
    for (int dt = 0; dt < 4; dt++)
#pragma unroll
        for (int nt = 0; nt < 2; nt++) oacc[dt][nt] = (f32x4){0.f, 0.f, 0.f, 0.f};
    float lsum[2] = {0.f, 0.f};

    const int s_beg = cb * CHUNK;
    const int NIT = CHUNK / 64;

    // running global staging pointers
    const unsigned short* kgp  = kh + (size_t)(s_beg + wave * 16 + sl) * HD + scol;
    const unsigned short* vgp0 = vh + (size_t)(wave * 16 + sl) * SEQN + s_beg + scol;
    const unsigned short* vgp1 = vgp0 + (size_t)8 * SEQN;

    // prologue: stage chunk 0 into buf 0
    load_lds_16(kgp,          &kv[0][(wave * 2 + 0) * 512]);
    load_lds_16(kgp + 8 * HD, &kv[0][(wave * 2 + 1) * 512]);
    load_lds_16(vgp0, &kv[0][4096 + (wave * 2 + 0) * 512]);
    load_lds_16(vgp1, &kv[0][4096 + (wave * 2 + 1) * 512]);
    kgp += 64 * HD; vgp0 += 64; vgp1 += 64;

    auto compute = [&](const unsigned short* ksb) {
        // ---- S^T = K·Q^T over this wave's 32 s-rows, 32 t-cols
        short8 ka[2][2];
#pragma unroll
        for (int sm = 0; sm < 2; sm++) {
            ka[sm][0] = *(const short8*)(ksb + kaoff[sm][0]);
            ka[sm][1] = *(const short8*)(ksb + kaoff[sm][1]);
        }
        f32x4 sacc[2][2];
#pragma unroll
        for (int sm = 0; sm < 2; sm++)
#pragma unroll
            for (int nt = 0; nt < 2; nt++) {
                f32x4 z = (f32x4){0.f, 0.f, 0.f, 0.f};
                z = __builtin_amdgcn_mfma_f32_16x16x32_bf16(ka[sm][0], qf[nt][0], z, 0, 0, 0);
                sacc[sm][nt] = __builtin_amdgcn_mfma_f32_16x16x32_bf16(ka[sm][1], qf[nt][1], z, 0, 0, 0);
            }

        // ---- static softmax + pack BOTH s-subtiles into ONE full-K B-frag:
        // B element k=quad*8+j: j<4 -> sm0 reg j, j>=4 -> sm1 reg j-4.
        short8 pfull[2];
#pragma unroll
        for (int nt = 0; nt < 2; nt++) {
            float a0 = EXP2(sacc[0][nt][0]);
            float a1 = EXP2(sacc[0][nt][1]);
            float a2 = EXP2(sacc[0][nt][2]);
            float a3 = EXP2(sacc[0][nt][3]);
            float b0 = EXP2(sacc[1][nt][0]);
            float b1 = EXP2(sacc[1][nt][1]);
            float b2 = EXP2(sacc[1][nt][2]);
            float b3 = EXP2(sacc[1][nt][3]);
            lsum[nt] += ((a0 + a1) + (a2 + a3)) + ((b0 + b1) + (b2 + b3));
            pfull[nt] = frag4(pkbf(a0, a1), pkbf(a2, a3), pkbf(b0, b1), pkbf(b2, b3));
        }

        // ---- O^T += V^T·P^T, full K=32: va dwords 0,1 = sm0 piece, 2,3 = sm1
#pragma unroll
        for (int dt = 0; dt < 4; dt++) {
            uint2 v0 = *(const uint2*)(ksb + vpoff[dt][0]);
            uint2 v1 = *(const uint2*)(ksb + vpoff[dt][1]);
            short8 va = frag4(v0.x, v0.y, v1.x, v1.y);
#pragma unroll
            for (int nt = 0; nt < 2; nt++)
                oacc[dt][nt] = __builtin_amdgcn_mfma_f32_16x16x32_bf16(va, pfull[nt], oacc[dt][nt], 0, 0, 0);
        }
    };

    for (int it2 = 0; it2 < NIT / 2; it2++) {
        // even iter: compute buf0, stage into buf1
        __syncthreads();
        load_lds_16(kgp,          &kv[1][(wave * 2 + 0) * 512]);
        load_lds_16(kgp + 8 * HD, &kv[1][(wave * 2 + 1) * 512]);
        load_lds_16(vgp0, &kv[1][4096 + (wave * 2 + 0) * 512]);
        load_lds_16(vgp1, &kv[1][4096 + (wave * 2 + 1) * 512]);
        kgp += 64 * HD; vgp0 += 64; vgp1 += 64;
        compute(&kv[0][0]);
        // odd iter: compute buf1, stage into buf0 (except last)
        __syncthreads();
        if (it2 + 1 < NIT / 2) {
            load_lds_16(kgp,          &kv[0][(wave * 2 + 0) * 512]);
            load_lds_16(kgp + 8 * HD, &kv[0][(wave * 2 + 1) * 512]);
            load_lds_16(vgp0, &kv[0][4096 + (wave * 2 + 0) * 512]);
            load_lds_16(vgp1, &kv[0][4096 + (wave * 2 + 1) * 512]);
            kgp += 64 * HD; vgp0 += 64; vgp1 += 64;
        }
        compute(&kv[1][0]);
    }

    // ---- cross-wave (s-half pair) reduction through LDS
    __syncthreads();
    unsigned int* exg = (unsigned int*)&kv[0][0];
#pragma unroll
    for (int nt = 0; nt < 2; nt++) {
        lsum[nt] += __shfl_xor(lsum[nt], 16);
        lsum[nt] += __shfl_xor(lsum[nt], 32);
    }
    if (quad == 0) {
        lredm[wave][0][l15] = lsum[0];
        lredm[wave][1][l15] = lsum[1];
    }
#pragma unroll
    for (int j = 0; j < 2; j++) {
        const int dt = (ws ^ 1) * 2 + j;      // the d-half I do NOT own
#pragma unroll
        for (int nt = 0; nt < 2; nt++) {
            const int idx = (((wave * 2 + j) * 2 + nt) * 64 + lane) * 2;
            exg[idx]     = pkbf(oacc[dt][nt][0], oacc[dt][nt][1]);
            exg[idx + 1] = pkbf(oacc[dt][nt][2], oacc[dt][nt][3]);
        }
    }
    __syncthreads();
    const int pw = wave ^ 2;                  // partner: other s-half, same t-half
    float lt[2];
#pragma unroll
    for (int nt = 0; nt < 2; nt++)
        lt[nt] = lredm[wave][nt][l15] + lredm[pw][nt][l15];

#pragma unroll
    for (int j = 0; j < 2; j++) {
        const int dtm = ws * 2 + j;           // my owned d-tiles
#pragma unroll
        for (int nt = 0; nt < 2; nt++) {
            const int idx = (((pw * 2 + j) * 2 + nt) * 64 + lane) * 2;
            unsigned int r0 = exg[idx], r1 = exg[idx + 1];
            f32x4 o = oacc[dtm][nt];
            o[0] += lo_f(r0); o[1] += hi_f(r0);
            o[2] += lo_f(r1); o[3] += hi_f(r1);
            const float rl = 1.0f / lt[nt];
            const int t = tb + wt * 32 + nt * 16 + l15;
            ushort4 ov;
            ov.x = f2bf(o[0] * rl); ov.y = f2bf(o[1] * rl);
            ov.z = f2bf(o[2] * rl); ov.w = f2bf(o[3] * rl);
            *(ushort4*)(po + ((size_t)(cb * NH + h) * SEQN + t) * HD + dtm * 16 + quad * 4) = ov;
            if (ws == 0 && quad == 0 && j == 0)
                ml[(size_t)(cb * NH + h) * SEQN + t] = make_float2(0.f, lt[nt]);
        }
    }
}

// ---------------- merge s-chunks (weights = per-chunk l) -> attnoT [t][c] bf16
__global__ __launch_bounds__(256) void attn_merge(const unsigned short* __restrict__ po,
                                                  const float2* __restrict__ ml,
                                                  unsigned short* __restrict__ attnoT) {
    const int idx = blockIdx.x * 256 + threadIdx.x;
    const int t  = idx >> 7;
    const int c4 = (idx & 127) << 2;
    const int h  = c4 >> 6;
    const int d  = c4 & 63;

    float a0 = 0.f, a1 = 0.f, a2 = 0.f, a3 = 0.f, denom = 0.f;
#pragma unroll
    for (int cb = 0; cb < SC; cb++) {
        float wgt = ml[(size_t)(cb * NH + h) * SEQN + t].y;
        denom += wgt;
        ushort4 o = *(const ushort4*)(po + ((size_t)(cb * NH + h) * SEQN + t) * HD + d);
        a0 += wgt * bf2f(o.x);
        a1 += wgt * bf2f(o.y);
        a2 += wgt * bf2f(o.z);
        a3 += wgt * bf2f(o.w);
    }
    const float rd = 1.0f / denom;
    ushort4 r;
    r.x = f2bf(a0 * rd); r.y = f2bf(a1 * rd); r.z = f2bf(a2 * rd); r.w = f2bf(a3 * rd);
    *(ushort4*)(attnoT + (size_t)t * CCH + c4) = r;
}

extern "C" void kernel_launch(void* const* d_in, const int* in_sizes, int n_in,
                              void* d_out, int out_size, void* d_ws, size_t ws_size,
                              hipStream_t stream) {
    const float* x      = (const float*)d_in[0];
    const float* gn_w   = (const float*)d_in[1];
    const float* gn_b   = (const float*)d_in[2];
    const float* qkv_w  = (const float*)d_in[3];
    const float* qkv_b  = (const float*)d_in[4];
    const float* proj_w = (const float*)d_in[5];
    const float* proj_b = (const float*)d_in[6];
    float* out = (float*)d_out;

    char* ws = (char*)d_ws;
    float2* partials = (float2*)ws;                                // 2 KB
    unsigned short* xnT   = (unsigned short*)(ws + 2048);          // 4096*512
    unsigned short* wq_bf = xnT + (size_t)SEQN * CCH;              // 1536*512
    unsigned short* wp_bf = wq_bf + (size_t)3 * CCH * CCH;         // 512*512
    unsigned short* qt    = wp_bf + (size_t)CCH * CCH;             // 8*4096*64
    unsigned short* kt    = qt + (size_t)NH * SEQN * HD;
    unsigned short* vv    = kt + (size_t)NH * SEQN * HD;
    unsigned short* po    = vv + (size_t)NH * SEQN * HD;           // SC*8*4096*64
    unsigned short* attnoT = po + (size_t)SC * NH * SEQN * HD;     // 4096*512
    float2* ml = (float2*)(attnoT + (size_t)SEQN * CCH);           // SC*8*4096

    prep<<<256 + (3 * CCH * CCH + CCH * CCH) / 4 / 256, 256, 0, stream>>>(
        x, partials, qkv_w, proj_w, wq_bf, wp_bf);
    gn_norm_t<<<dim3(SEQN / 64, CCH / 64), 256, 0, stream>>>(x, partials, gn_w, gn_b, xnT);
    gemm_qkv<<<dim3(SEQN / 128, 3 * CCH / 64), 256, 0, stream>>>(wq_bf, xnT, qkv_b, qt, kt, vv);
    attn<<<dim3(SEQN / 64, SC, NH), 256, 0, stream>>>(qt, kt, vv, po, ml);
    attn_merge<<<SEQN * 128 / 256, 256, 0, stream>>>(po, ml, attnoT);
    gemm_proj<<<dim3(SEQN / 128, CCH / 64), 256, 0, stream>>>(wp_bf, attnoT, proj_b, x, out);
}

// Round 9
// 193.643 us; speedup vs baseline: 1.4395x; 1.0065x over previous
//
#include <hip/hip_runtime.h>
#include <hip/hip_bf16.h>

#define SEQN 4096
#define HD 64
#define CCH 512
#define NH 8
#define SC 4            // s-split chunks
#define CHUNK (SEQN / SC)

typedef __attribute__((ext_vector_type(8))) short short8;   // 8 bf16 (4 VGPRs)
typedef __attribute__((ext_vector_type(4))) float f32x4;    // 4 fp32 acc

#define AS1 __attribute__((address_space(1)))
#define AS3 __attribute__((address_space(3)))

#if __has_builtin(__builtin_amdgcn_exp2f)
#define EXP2(x) __builtin_amdgcn_exp2f(x)
#else
#define EXP2(x) exp2f(x)
#endif

// 0.125 * log2(e): fold attention scale AND exp->exp2 conversion into Q
#define QSCALE 0.18033688011112042f

static __device__ __forceinline__ unsigned short f2bf(float f) {
    __hip_bfloat16 h = __float2bfloat16(f);
    return *(unsigned short*)&h;
}
static __device__ __forceinline__ float bf2f(unsigned short u) {
    unsigned int v = ((unsigned int)u) << 16;
    return *(float*)&v;
}
static __device__ __forceinline__ unsigned int fbits(float f) { return *(unsigned int*)&f; }
static __device__ __forceinline__ float hi_f(unsigned int v) {
    unsigned int t = v & 0xFFFF0000u; return *(float*)&t;
}
static __device__ __forceinline__ float lo_f(unsigned int v) {
    unsigned int t = v << 16; return *(float*)&t;
}
static __device__ __forceinline__ unsigned int pkbf(float lo, float hi) {
    return (fbits(hi) & 0xFFFF0000u) | (fbits(lo) >> 16);
}
// full-K fragment from 4 dwords (bit_cast, no union — unions force scratch)
static __device__ __forceinline__ short8 frag4(unsigned int a, unsigned int b,
                                               unsigned int c, unsigned int d) {
    uint4 u; u.x = a; u.y = b; u.z = c; u.w = d;
    return __builtin_bit_cast(short8, u);
}
static __device__ __forceinline__ void load_lds_16(const unsigned short* g, unsigned short* l) {
    __builtin_amdgcn_global_load_lds((const AS1 void*)g, (AS3 void*)l, 16, 0, 0);
}

// ---------------- prep: GN partial stats (blocks 0..255) + weight cvt (rest)
__global__ __launch_bounds__(256) void prep(const float* __restrict__ x,
                                            float2* __restrict__ partials,
                                            const float* __restrict__ qkv_w,
                                            const float* __restrict__ proj_w,
                                            unsigned short* __restrict__ wq,
                                            unsigned short* __restrict__ wp) {
    const int tid = threadIdx.x;
    if (blockIdx.x < 256) {
        const int b = blockIdx.x;
        const int g = b >> 3;
        const int slice = b & 7;
        const float* xs = x + (size_t)g * 65536 + slice * 8192;
        float s = 0.f, ss = 0.f;
        for (int i = tid; i < 2048; i += 256) {
            float4 v = ((const float4*)xs)[i];
            s  += v.x + v.y + v.z + v.w;
            ss += v.x * v.x + v.y * v.y + v.z * v.z + v.w * v.w;
        }
        for (int off = 32; off; off >>= 1) {
            s  += __shfl_xor(s, off);
            ss += __shfl_xor(ss, off);
        }
        __shared__ float red[8];
        const int wave = tid >> 6;
        const int lane = tid & 63;
        if (lane == 0) { red[wave] = s; red[4 + wave] = ss; }
        __syncthreads();
        if (tid == 0)
            partials[b] = make_float2(red[0] + red[1] + red[2] + red[3],
                                      red[4] + red[5] + red[6] + red[7]);
    } else {
        const int i = (blockIdx.x - 256) * 256 + tid;
        const int NQ = 3 * CCH * CCH / 4;
        float4 f;
        unsigned short* d;
        if (i < NQ) { f = ((const float4*)qkv_w)[i]; d = wq + (size_t)i * 4; }
        else        { f = ((const float4*)proj_w)[i - NQ]; d = wp + (size_t)(i - NQ) * 4; }
        ushort4 o;
        o.x = f2bf(f.x); o.y = f2bf(f.y); o.z = f2bf(f.z); o.w = f2bf(f.w);
        *(ushort4*)d = o;
    }
}

// ---------------- GroupNorm finalize + apply + transpose: x[c][t] -> xnT[t][c] bf16
__global__ __launch_bounds__(256) void gn_norm_t(const float* __restrict__ x,
                                                 const float2* __restrict__ partials,
                                                 const float* __restrict__ w,
                                                 const float* __restrict__ b,
                                                 unsigned short* __restrict__ xnT) {
    __shared__ float tile[64][65];
    __shared__ float gmean[4], grstd[4];
    const int t0 = blockIdx.x * 64;
    const int c0 = blockIdx.y * 64;
    const int tid = threadIdx.x;
    if (tid < 4) {
        int g = (c0 >> 4) + tid;
        float s = 0.f, ss = 0.f;
#pragma unroll
        for (int i = 0; i < 8; i++) {
            float2 p = partials[g * 8 + i];
            s += p.x; ss += p.y;
        }
        float mean = s * (1.f / 65536.f);
        float var  = ss * (1.f / 65536.f) - mean * mean;
        gmean[tid] = mean;
        grstd[tid] = rsqrtf(var + 1e-5f);
    }
    __syncthreads();
    for (int e = tid; e < 1024; e += 256) {
        int r  = e >> 4;
        int t4 = (e & 15) << 2;
        int c = c0 + r;
        float rstd = grstd[r >> 4];
        float sc = w[c] * rstd;
        float sh = b[c] - gmean[r >> 4] * sc;
        float4 v = *(const float4*)(x + (size_t)c * SEQN + t0 + t4);
        tile[r][t4 + 0] = v.x * sc + sh;
        tile[r][t4 + 1] = v.y * sc + sh;
        tile[r][t4 + 2] = v.z * sc + sh;
        tile[r][t4 + 3] = v.w * sc + sh;
    }
    __syncthreads();
    for (int e = tid; e < 1024; e += 256) {
        int t  = e >> 4;
        int c4 = (e & 15) << 2;
        ushort4 o;
        o.x = f2bf(tile[c4 + 0][t]);
        o.y = f2bf(tile[c4 + 1][t]);
        o.z = f2bf(tile[c4 + 2][t]);
        o.w = f2bf(tile[c4 + 3][t]);
        *(ushort4*)(xnT + (size_t)(t0 + t) * CCH + c0 + c4) = o;
    }
}

// ---------------- QKV GEMM: 64x128 tile, BK=64, LDS-staged; fused epilogue
// -> qt/kt [h][t][d] bf16 (Q scaled QSCALE), vv [c][t] bf16.
__global__ __launch_bounds__(256) void gemm_qkv(const unsigned short* __restrict__ Wb,
                                                const unsigned short* __restrict__ xnT,
                                                const float* __restrict__ bias,
                                                unsigned short* __restrict__ qt,
                                                unsigned short* __restrict__ kt,
                                                unsigned short* __restrict__ vv) {
    __shared__ __align__(16) unsigned short Asm[64 * 64];
    __shared__ __align__(16) unsigned short Bsm[128 * 64];
    const int tid = threadIdx.x;
    const int wave = tid >> 6;
    const int lane = tid & 63;
    const int quad = lane >> 4;
    const int l15  = lane & 15;
    const int wm = wave >> 1, wn = wave & 1;
    const int nb = blockIdx.x, mb = blockIdx.y;
    const int sl = lane >> 3, slot = lane & 7;
    const int scol = (slot ^ sl) * 8;

    f32x4 acc[2][4];
#pragma unroll
    for (int mt = 0; mt < 2; mt++)
#pragma unroll
        for (int nt = 0; nt < 4; nt++) acc[mt][nt] = (f32x4){0.f, 0.f, 0.f, 0.f};

    for (int kb = 0; kb < CCH; kb += 64) {
        __syncthreads();
#pragma unroll
        for (int i = 0; i < 2; i++) {
            const int c = wave * 2 + i;
            const int row = c * 8 + sl;
            load_lds_16(Wb + (size_t)(mb * 64 + row) * CCH + kb + scol, &Asm[c * 512]);
        }
#pragma unroll
        for (int i = 0; i < 4; i++) {
            const int c = wave * 4 + i;
            const int row = c * 8 + sl;
            load_lds_16(xnT + (size_t)(nb * 128 + row) * CCH + kb + scol, &Bsm[c * 512]);
        }
        __syncthreads();
#pragma unroll
        for (int kk = 0; kk < 2; kk++) {
            const int so = ((kk * 4 + quad) ^ (l15 & 7)) << 3;
            short8 a[2], b[4];
#pragma unroll
            for (int mt = 0; mt < 2; mt++)
                a[mt] = *(const short8*)(Asm + (wm * 32 + mt * 16 + l15) * 64 + so);
#pragma unroll
            for (int nt = 0; nt < 4; nt++)
                b[nt] = *(const short8*)(Bsm + (wn * 64 + nt * 16 + l15) * 64 + so);
#pragma unroll
            for (int mt = 0; mt < 2; mt++)
#pragma unroll
                for (int nt = 0; nt < 4; nt++)
                    acc[mt][nt] = __builtin_amdgcn_mfma_f32_16x16x32_bf16(a[mt], b[nt], acc[mt][nt], 0, 0, 0);
        }
    }

    const int sel = mb >> 3;                 // 64-row blocks: 0..7=Q, 8..15=K, 16..23=V
#pragma unroll
    for (int mt = 0; mt < 2; mt++) {
        const int m0 = mb * 64 + wm * 32 + mt * 16 + quad * 4;
        float bs[4] = {bias[m0], bias[m0 + 1], bias[m0 + 2], bias[m0 + 3]};
        if (sel < 2) {
            unsigned short* dst = sel ? kt : qt;
            const float mul = sel ? 1.0f : QSCALE;
            const int h  = (m0 >> 6) & 7;
            const int d0 = m0 & 63;
#pragma unroll
            for (int nt = 0; nt < 4; nt++) {
                const int t = nb * 128 + wn * 64 + nt * 16 + l15;
                ushort4 o;
                o.x = f2bf((acc[mt][nt][0] + bs[0]) * mul);
                o.y = f2bf((acc[mt][nt][1] + bs[1]) * mul);
                o.z = f2bf((acc[mt][nt][2] + bs[2]) * mul);
                o.w = f2bf((acc[mt][nt][3] + bs[3]) * mul);
                *(ushort4*)(dst + ((size_t)h * SEQN + t) * HD + d0) = o;
            }
        } else {
            const int c0 = m0 - 1024;
#pragma unroll
            for (int nt = 0; nt < 4; nt++) {
                const int t = nb * 128 + wn * 64 + nt * 16 + l15;
#pragma unroll
                for (int reg = 0; reg < 4; reg++)
                    vv[(size_t)(c0 + reg) * SEQN + t] = f2bf(acc[mt][nt][reg] + bs[reg]);
            }
        }
    }
}

// ---------------- proj GEMM: 64x128 tile, BK=64, LDS-staged; +bias+resid fp32 out
__global__ __launch_bounds__(256) void gemm_proj(const unsigned short* __restrict__ Wb,
                                                 const unsigned short* __restrict__ attnoT,
                                                 const float* __restrict__ bias,
                                                 const float* __restrict__ resid,
                                                 float* __restrict__ out) {
    __shared__ __align__(16) unsigned short Asm[64 * 64];
    __shared__ __align__(16) unsigned short Bsm[128 * 64];
    const int tid = threadIdx.x;
    const int wave = tid >> 6;
    const int lane = tid & 63;
    const int quad = lane >> 4;
    const int l15  = lane & 15;
    const int wm = wave >> 1, wn = wave & 1;
    const int nb = blockIdx.x, mb = blockIdx.y;
    const int sl = lane >> 3, slot = lane & 7;
    const int scol = (slot ^ sl) * 8;

    f32x4 acc[2][4];
#pragma unroll
    for (int mt = 0; mt < 2; mt++)
#pragma unroll
        for (int nt = 0; nt < 4; nt++) acc[mt][nt] = (f32x4){0.f, 0.f, 0.f, 0.f};

    for (int kb = 0; kb < CCH; kb += 64) {
        __syncthreads();
#pragma unroll
        for (int i = 0; i < 2; i++) {
            const int c = wave * 2 + i;
            const int row = c * 8 + sl;
            load_lds_16(Wb + (size_t)(mb * 64 + row) * CCH + kb + scol, &Asm[c * 512]);
        }
#pragma unroll
        for (int i = 0; i < 4; i++) {
            const int c = wave * 4 + i;
            const int row = c * 8 + sl;
            load_lds_16(attnoT + (size_t)(nb * 128 + row) * CCH + kb + scol, &Bsm[c * 512]);
        }
        __syncthreads();
#pragma unroll
        for (int kk = 0; kk < 2; kk++) {
            const int so = ((kk * 4 + quad) ^ (l15 & 7)) << 3;
            short8 a[2], b[4];
#pragma unroll
            for (int mt = 0; mt < 2; mt++)
                a[mt] = *(const short8*)(Asm + (wm * 32 + mt * 16 + l15) * 64 + so);
#pragma unroll
            for (int nt = 0; nt < 4; nt++)
                b[nt] = *(const short8*)(Bsm + (wn * 64 + nt * 16 + l15) * 64 + so);
#pragma unroll
            for (int mt = 0; mt < 2; mt++)
#pragma unroll
                for (int nt = 0; nt < 4; nt++)
                    acc[mt][nt] = __builtin_amdgcn_mfma_f32_16x16x32_bf16(a[mt], b[nt], acc[mt][nt], 0, 0, 0);
        }
    }

#pragma unroll
    for (int mt = 0; mt < 2; mt++) {
        const int m0 = mb * 64 + wm * 32 + mt * 16 + quad * 4;
        float bs[4] = {bias[m0], bias[m0 + 1], bias[m0 + 2], bias[m0 + 3]};
#pragma unroll
        for (int nt = 0; nt < 4; nt++) {
            const int n = nb * 128 + wn * 64 + nt * 16 + l15;
#pragma unroll
            for (int reg = 0; reg < 4; reg++) {
                const size_t off = (size_t)(m0 + reg) * SEQN + n;
                out[off] = acc[mt][nt][reg] + bs[reg] + resid[off];
            }
        }
    }
}

// ---------------- Flash attention: identical compute to round 8, but 1-D grid
// with XCD-aware decode: h = bid & 7 pins each head's blocks to one XCD so all
// K/V/Q staging reads hit the LOCAL 4MB L2 slice (head K+V+Q = 2MB).
__global__ __launch_bounds__(256) void attn(const unsigned short* __restrict__ qt,
                                            const unsigned short* __restrict__ kt,
                                            const unsigned short* __restrict__ vv,
                                            unsigned short* __restrict__ po,
                                            float2* __restrict__ ml) {
    const int tid  = threadIdx.x;
    const int wave = tid >> 6;
    const int lane = tid & 63;
    const int quad = lane >> 4;
    const int l15  = lane & 15;
    const int ws = wave >> 1;      // s-half owner (32 s)
    const int wt = wave & 1;       // t-half owner (32 t)
    // XCD-aware decode: round-robin dispatch puts bid%8 on XCD bid%8.
    const int bid = blockIdx.x;
    const int h   = bid & 7;               // head -> XCD pin
    const int r   = bid >> 3;
    const int cb  = r >> 6;
    const int tb  = (r & 63) * 64;

    const unsigned short* qh = qt + (size_t)h * SEQN * HD;
    const unsigned short* kh = kt + (size_t)h * SEQN * HD;
    const unsigned short* vh = vv + (size_t)h * HD * SEQN;

    // kv[buf][0..4095] = K tile (64 s x 64 d, swizzled); [4096..8191] = V (64 d x 64 s)
    __shared__ __align__(16) unsigned short kv[2][8192];
    __shared__ float lredm[4][2][16];

    const int sl = lane >> 3, slot = lane & 7;
    const int scol = (slot ^ sl) * 8;
    const int x7 = l15 & 7;

    // hoisted LDS element offsets
    int kaoff[2][2];
#pragma unroll
    for (int sm = 0; sm < 2; sm++)
#pragma unroll
        for (int k = 0; k < 2; k++)
            kaoff[sm][k] = (ws * 32 + sm * 16 + l15) * 64 + (((k * 4 + quad) ^ x7) << 3);
    int vpoff[4][2];
#pragma unroll
    for (int dt = 0; dt < 4; dt++)
#pragma unroll
        for (int sm = 0; sm < 2; sm++)
            vpoff[dt][sm] = 4096 + (dt * 16 + l15) * 64 +
                            (((ws * 4 + sm * 2 + (quad >> 1)) ^ x7) << 3) + ((quad & 1) << 2);

    // Q B-frags persistent: B[k=d][n=t] for this wave's 2 t-tiles
    short8 qf[2][2];
#pragma unroll
    for (int nt = 0; nt < 2; nt++) {
        const unsigned short* qp = qh + (size_t)(tb + wt * 32 + nt * 16 + l15) * HD + quad * 8;
        qf[nt][0] = *(const short8*)(qp);
        qf[nt][1] = *(const short8*)(qp + 32);
    }

    f32x4 oacc[4][2];   // [d-tile 0..3][t-tile 0..1], this wave's s-half partial
#pragma unroll
    for (int dt = 0; dt < 4; dt++)
#pragma unroll
        for (int nt = 0; nt < 2; nt++) oacc[dt][nt] = (f32x4){0.f, 0.f, 0.f, 0.f};
    float lsum[2] = {0.f, 0.f};

    const int s_beg = cb * CHUNK;
    const int NIT = CHUNK / 64;

    // running global staging pointers
    const unsigned short* kgp  = kh + (size_t)(s_beg + wave * 16 + sl) * HD + scol;
    const unsigned short* vgp0 = vh + (size_t)(wave * 16 + sl) * SEQN + s_beg + scol;
    const unsigned short* vgp1 = vgp0 + (size_t)8 * SEQN;

    // prologue: stage chunk 0 into buf 0
    load_lds_16(kgp,          &kv[0][(wave * 2 + 0) * 512]);
    load_lds_16(kgp + 8 * HD, &kv[0][(wave * 2 + 1) * 512]);
    load_lds_16(vgp0, &kv[0][4096 + (wave * 2 + 0) * 512]);
    load_lds_16(vgp1, &kv[0][4096 + (wave * 2 + 1) * 512]);
    kgp += 64 * HD; vgp0 += 64; vgp1 += 64;

    auto compute = [&](const unsigned short* ksb) {
        // ---- S^T = K·Q^T over this wave's 32 s-rows, 32 t-cols
        short8 ka[2][2];
#pragma unroll
        for (int sm = 0; sm < 2; sm++) {
            ka[sm][0] = *(const short8*)(ksb + kaoff[sm][0]);
            ka[sm][1] = *(const short8*)(ksb + kaoff[sm][1]);
        }
        f32x4 sacc[2][2];
#pragma unroll
        for (int sm = 0; sm < 2; sm++)
#pragma unroll
            for (int nt = 0; nt < 2; nt++) {
                f32x4 z = (f32x4){0.f, 0.f, 0.f, 0.f};
                z = __builtin_amdgcn_mfma_f32_16x16x32_bf16(ka[sm][0], qf[nt][0], z, 0, 0, 0);
                sacc[sm][nt] = __builtin_amdgcn_mfma_f32_16x16x32_bf16(ka[sm][1], qf[nt][1], z, 0, 0, 0);
            }

        // ---- static softmax + pack BOTH s-subtiles into ONE full-K B-frag
        short8 pfull[2];
#pragma unroll
        for (int nt = 0; nt < 2; nt++) {
            float a0 = EXP2(sacc[0][nt][0]);
            float a1 = EXP2(sacc[0][nt][1]);
            float a2 = EXP2(sacc[0][nt][2]);
            float a3 = EXP2(sacc[0][nt][3]);
            float b0 = EXP2(sacc[1][nt][0]);
            float b1 = EXP2(sacc[1][nt][1]);
            float b2 = EXP2(sacc[1][nt][2]);
            float b3 = EXP2(sacc[1][nt][3]);
            lsum[nt] += ((a0 + a1) + (a2 + a3)) + ((b0 + b1) + (b2 + b3));
            pfull[nt] = frag4(pkbf(a0, a1), pkbf(a2, a3), pkbf(b0, b1), pkbf(b2, b3));
        }

        // ---- O^T += V^T·P^T, full K=32
#pragma unroll
        for (int dt = 0; dt < 4; dt++) {
            uint2 v0 = *(const uint2*)(ksb + vpoff[dt][0]);
            uint2 v1 = *(const uint2*)(ksb + vpoff[dt][1]);
            short8 va = frag4(v0.x, v0.y, v1.x, v1.y);
#pragma unroll
            for (int nt = 0; nt < 2; nt++)
                oacc[dt][nt] = __builtin_amdgcn_mfma_f32_16x16x32_bf16(va, pfull[nt], oacc[dt][nt], 0, 0, 0);
        }
    };

    for (int it2 = 0; it2 < NIT / 2; it2++) {
        // even iter: compute buf0, stage into buf1
        __syncthreads();
        load_lds_16(kgp,          &kv[1][(wave * 2 + 0) * 512]);
        load_lds_16(kgp + 8 * HD, &kv[1][(wave * 2 + 1) * 512]);
        load_lds_16(vgp0, &kv[1][4096 + (wave * 2 + 0) * 512]);
        load_lds_16(vgp1, &kv[1][4096 + (wave * 2 + 1) * 512]);
        kgp += 64 * HD; vgp0 += 64; vgp1 += 64;
        compute(&kv[0][0]);
        // odd iter: compute buf1, stage into buf0 (except last)
        __syncthreads();
        if (it2 + 1 < NIT / 2) {
            load_lds_16(kgp,          &kv[0][(wave * 2 + 0) * 512]);
            load_lds_16(kgp + 8 * HD, &kv[0][(wave * 2 + 1) * 512]);
            load_lds_16(vgp0, &kv[0][4096 + (wave * 2 + 0) * 512]);
            load_lds_16(vgp1, &kv[0][4096 + (wave * 2 + 1) * 512]);
            kgp += 64 * HD; vgp0 += 64; vgp1 += 64;
        }
        compute(&kv[1][0]);
    }

    // ---- cross-wave (s-half pair) reduction through LDS
    __syncthreads();
    unsigned int* exg = (unsigned int*)&kv[0][0];
#pragma unroll
    for (int nt = 0; nt < 2; nt++) {
        lsum[nt] += __shfl_xor(lsum[nt], 16);
        lsum[nt] += __shfl_xor(lsum[nt], 32);
    }
    if (quad == 0) {
        lredm[wave][0][l15] = lsum[0];
        lredm[wave][1][l15] = lsum[1];
    }
#pragma unroll
    for (int j = 0; j < 2; j++) {
        const int dt = (ws ^ 1) * 2 + j;      // the d-half I do NOT own
#pragma unroll
        for (int nt = 0; nt < 2; nt++) {
            const int idx = (((wave * 2 + j) * 2 + nt) * 64 + lane) * 2;
            exg[idx]     = pkbf(oacc[dt][nt][0], oacc[dt][nt][1]);
            exg[idx + 1] = pkbf(oacc[dt][nt][2], oacc[dt][nt][3]);
        }
    }
    __syncthreads();
    const int pw = wave ^ 2;                  // partner: other s-half, same t-half
    float lt[2];
#pragma unroll
    for (int nt = 0; nt < 2; nt++)
        lt[nt] = lredm[wave][nt][l15] + lredm[pw][nt][l15];

#pragma unroll
    for (int j = 0; j < 2; j++) {
        const int dtm = ws * 2 + j;           // my owned d-tiles
#pragma unroll
        for (int nt = 0; nt < 2; nt++) {
            const int idx = (((pw * 2 + j) * 2 + nt) * 64 + lane) * 2;
            unsigned int r0 = exg[idx], r1 = exg[idx + 1];
            f32x4 o = oacc[dtm][nt];
            o[0] += lo_f(r0); o[1] += hi_f(r0);
            o[2] += lo_f(r1); o[3] += hi_f(r1);
            const float rl = 1.0f / lt[nt];
            const int t = tb + wt * 32 + nt * 16 + l15;
            ushort4 ov;
            ov.x = f2bf(o[0] * rl); ov.y = f2bf(o[1] * rl);
            ov.z = f2bf(o[2] * rl); ov.w = f2bf(o[3] * rl);
            *(ushort4*)(po + ((size_t)(cb * NH + h) * SEQN + t) * HD + dtm * 16 + quad * 4) = ov;
            if (ws == 0 && quad == 0 && j == 0)
                ml[(size_t)(cb * NH + h) * SEQN + t] = make_float2(0.f, lt[nt]);
        }
    }
}

// ---------------- merge s-chunks (weights = per-chunk l) -> attnoT [t][c] bf16
__global__ __launch_bounds__(256) void attn_merge(const unsigned short* __restrict__ po,
                                                  const float2* __restrict__ ml,
                                                  unsigned short* __restrict__ attnoT) {
    const int idx = blockIdx.x * 256 + threadIdx.x;
    const int t  = idx >> 7;
    const int c4 = (idx & 127) << 2;
    const int h  = c4 >> 6;
    const int d  = c4 & 63;

    float a0 = 0.f, a1 = 0.f, a2 = 0.f, a3 = 0.f, denom = 0.f;
#pragma unroll
    for (int cb = 0; cb < SC; cb++) {
        float wgt = ml[(size_t)(cb * NH + h) * SEQN + t].y;
        denom += wgt;
        ushort4 o = *(const ushort4*)(po + ((size_t)(cb * NH + h) * SEQN + t) * HD + d);
        a0 += wgt * bf2f(o.x);
        a1 += wgt * bf2f(o.y);
        a2 += wgt * bf2f(o.z);
        a3 += wgt * bf2f(o.w);
    }
    const float rd = 1.0f / denom;
    ushort4 r;
    r.x = f2bf(a0 * rd); r.y = f2bf(a1 * rd); r.z = f2bf(a2 * rd); r.w = f2bf(a3 * rd);
    *(ushort4*)(attnoT + (size_t)t * CCH + c4) = r;
}

extern "C" void kernel_launch(void* const* d_in, const int* in_sizes, int n_in,
                              void* d_out, int out_size, void* d_ws, size_t ws_size,
                              hipStream_t stream) {
    const float* x      = (const float*)d_in[0];
    const float* gn_w   = (const float*)d_in[1];
    const float* gn_b   = (const float*)d_in[2];
    const float* qkv_w  = (const float*)d_in[3];
    const float* qkv_b  = (const float*)d_in[4];
    const float* proj_w = (const float*)d_in[5];
    const float* proj_b = (const float*)d_in[6];
    float* out = (float*)d_out;

    char* ws = (char*)d_ws;
    float2* partials = (float2*)ws;                                // 2 KB
    unsigned short* xnT   = (unsigned short*)(ws + 2048);          // 4096*512
    unsigned short* wq_bf = xnT + (size_t)SEQN * CCH;              // 1536*512
    unsigned short* wp_bf = wq_bf + (size_t)3 * CCH * CCH;         // 512*512
    unsigned short* qt    = wp_bf + (size_t)CCH * CCH;             // 8*4096*64
    unsigned short* kt    = qt + (size_t)NH * SEQN * HD;
    unsigned short* vv    = kt + (size_t)NH * SEQN * HD;
    unsigned short* po    = vv + (size_t)NH * SEQN * HD;           // SC*8*4096*64
    unsigned short* attnoT = po + (size_t)SC * NH * SEQN * HD;     // 4096*512
    float2* ml = (float2*)(attnoT + (size_t)SEQN * CCH);           // SC*8*4096

    prep<<<256 + (3 * CCH * CCH + CCH * CCH) / 4 / 256, 256, 0, stream>>>(
        x, partials, qkv_w, proj_w, wq_bf, wp_bf);
    gn_norm_t<<<dim3(SEQN / 64, CCH / 64), 256, 0, stream>>>(x, partials, gn_w, gn_b, xnT);
    gemm_qkv<<<dim3(SEQN / 128, 3 * CCH / 64), 256, 0, stream>>>(wq_bf, xnT, qkv_b, qt, kt, vv);
    attn<<<SEQN / 64 * SC * NH, 256, 0, stream>>>(qt, kt, vv, po, ml);
    attn_merge<<<SEQN * 128 / 256, 256, 0, stream>>>(po, ml, attnoT);
    gemm_proj<<<dim3(SEQN / 128, CCH / 64), 256, 0, stream>>>(wp_bf, attnoT, proj_b, x, out);
}

// Round 10
// 174.594 us; speedup vs baseline: 1.5965x; 1.1091x over previous
//
#include <hip/hip_runtime.h>
#include <hip/hip_bf16.h>

#define SEQN 4096
#define HD 64
#define CCH 512
#define NH 8
#define SC 4            // s-split chunks
#define CHUNK (SEQN / SC)

typedef __attribute__((ext_vector_type(8))) short short8;   // 8 bf16 (4 VGPRs)
typedef __attribute__((ext_vector_type(4))) float f32x4;    // 4 fp32 acc

#define AS1 __attribute__((address_space(1)))
#define AS3 __attribute__((address_space(3)))

#if __has_builtin(__builtin_amdgcn_exp2f)
#define EXP2(x) __builtin_amdgcn_exp2f(x)
#else
#define EXP2(x) exp2f(x)
#endif

// 0.125 * log2(e): fold attention scale AND exp->exp2 conversion into Q
#define QSCALE 0.18033688011112042f

static __device__ __forceinline__ unsigned short f2bf(float f) {
    __hip_bfloat16 h = __float2bfloat16(f);
    return *(unsigned short*)&h;
}
static __device__ __forceinline__ float bf2f(unsigned short u) {
    unsigned int v = ((unsigned int)u) << 16;
    return *(float*)&v;
}
static __device__ __forceinline__ unsigned int fbits(float f) { return *(unsigned int*)&f; }
static __device__ __forceinline__ float hi_f(unsigned int v) {
    unsigned int t = v & 0xFFFF0000u; return *(float*)&t;
}
static __device__ __forceinline__ float lo_f(unsigned int v) {
    unsigned int t = v << 16; return *(float*)&t;
}
static __device__ __forceinline__ unsigned int pkbf(float lo, float hi) {
    return (fbits(hi) & 0xFFFF0000u) | (fbits(lo) >> 16);
}
// full-K fragment from 4 dwords (bit_cast, no union — unions force scratch)
static __device__ __forceinline__ short8 frag4(unsigned int a, unsigned int b,
                                               unsigned int c, unsigned int d) {
    uint4 u; u.x = a; u.y = b; u.z = c; u.w = d;
    return __builtin_bit_cast(short8, u);
}
static __device__ __forceinline__ void load_lds_16(const unsigned short* g, unsigned short* l) {
    __builtin_amdgcn_global_load_lds((const AS1 void*)g, (AS3 void*)l, 16, 0, 0);
}

// ---------------- prep: GN partial stats (blocks 0..255) + weight cvt (rest)
__global__ __launch_bounds__(256) void prep(const float* __restrict__ x,
                                            float2* __restrict__ partials,
                                            const float* __restrict__ qkv_w,
                                            const float* __restrict__ proj_w,
                                            unsigned short* __restrict__ wq,
                                            unsigned short* __restrict__ wp) {
    const int tid = threadIdx.x;
    if (blockIdx.x < 256) {
        const int b = blockIdx.x;
        const int g = b >> 3;
        const int slice = b & 7;
        const float* xs = x + (size_t)g * 65536 + slice * 8192;
        float s = 0.f, ss = 0.f;
        for (int i = tid; i < 2048; i += 256) {
            float4 v = ((const float4*)xs)[i];
            s  += v.x + v.y + v.z + v.w;
            ss += v.x * v.x + v.y * v.y + v.z * v.z + v.w * v.w;
        }
        for (int off = 32; off; off >>= 1) {
            s  += __shfl_xor(s, off);
            ss += __shfl_xor(ss, off);
        }
        __shared__ float red[8];
        const int wave = tid >> 6;
        const int lane = tid & 63;
        if (lane == 0) { red[wave] = s; red[4 + wave] = ss; }
        __syncthreads();
        if (tid == 0)
            partials[b] = make_float2(red[0] + red[1] + red[2] + red[3],
                                      red[4] + red[5] + red[6] + red[7]);
    } else {
        const int i = (blockIdx.x - 256) * 256 + tid;
        const int NQ = 3 * CCH * CCH / 4;
        float4 f;
        unsigned short* d;
        if (i < NQ) { f = ((const float4*)qkv_w)[i]; d = wq + (size_t)i * 4; }
        else        { f = ((const float4*)proj_w)[i - NQ]; d = wp + (size_t)(i - NQ) * 4; }
        ushort4 o;
        o.x = f2bf(f.x); o.y = f2bf(f.y); o.z = f2bf(f.z); o.w = f2bf(f.w);
        *(ushort4*)d = o;
    }
}

// ---------------- GroupNorm finalize + apply + transpose: x[c][t] -> xnT[t][c] bf16
__global__ __launch_bounds__(256) void gn_norm_t(const float* __restrict__ x,
                                                 const float2* __restrict__ partials,
                                                 const float* __restrict__ w,
                                                 const float* __restrict__ b,
                                                 unsigned short* __restrict__ xnT) {
    __shared__ float tile[64][65];
    __shared__ float gmean[4], grstd[4];
    const int t0 = blockIdx.x * 64;
    const int c0 = blockIdx.y * 64;
    const int tid = threadIdx.x;
    if (tid < 4) {
        int g = (c0 >> 4) + tid;
        float s = 0.f, ss = 0.f;
#pragma unroll
        for (int i = 0; i < 8; i++) {
            float2 p = partials[g * 8 + i];
            s += p.x; ss += p.y;
        }
        float mean = s * (1.f / 65536.f);
        float var  = ss * (1.f / 65536.f) - mean * mean;
        gmean[tid] = mean;
        grstd[tid] = rsqrtf(var + 1e-5f);
    }
    __syncthreads();
    for (int e = tid; e < 1024; e += 256) {
        int r  = e >> 4;
        int t4 = (e & 15) << 2;
        int c = c0 + r;
        float rstd = grstd[r >> 4];
        float sc = w[c] * rstd;
        float sh = b[c] - gmean[r >> 4] * sc;
        float4 v = *(const float4*)(x + (size_t)c * SEQN + t0 + t4);
        tile[r][t4 + 0] = v.x * sc + sh;
        tile[r][t4 + 1] = v.y * sc + sh;
        tile[r][t4 + 2] = v.z * sc + sh;
        tile[r][t4 + 3] = v.w * sc + sh;
    }
    __syncthreads();
    for (int e = tid; e < 1024; e += 256) {
        int t  = e >> 4;
        int c4 = (e & 15) << 2;
        ushort4 o;
        o.x = f2bf(tile[c4 + 0][t]);
        o.y = f2bf(tile[c4 + 1][t]);
        o.z = f2bf(tile[c4 + 2][t]);
        o.w = f2bf(tile[c4 + 3][t]);
        *(ushort4*)(xnT + (size_t)(t0 + t) * CCH + c0 + c4) = o;
    }
}

// ---------------- QKV GEMM: 64x128 tile, BK=64, LDS-staged; fused epilogue
// -> qt/kt [h][t][d] bf16 (Q scaled QSCALE), vv [c][t] bf16.
__global__ __launch_bounds__(256) void gemm_qkv(const unsigned short* __restrict__ Wb,
                                                const unsigned short* __restrict__ xnT,
                                                const float* __restrict__ bias,
                                                unsigned short* __restrict__ qt,
                                                unsigned short* __restrict__ kt,
                                                unsigned short* __restrict__ vv) {
    __shared__ __align__(16) unsigned short Asm[64 * 64];
    __shared__ __align__(16) unsigned short Bsm[128 * 64];
    const int tid = threadIdx.x;
    const int wave = tid >> 6;
    const int lane = tid & 63;
    const int quad = lane >> 4;
    const int l15  = lane & 15;
    const int wm = wave >> 1, wn = wave & 1;
    const int nb = blockIdx.x, mb = blockIdx.y;
    const int sl = lane >> 3, slot = lane & 7;
    const int scol = (slot ^ sl) * 8;

    f32x4 acc[2][4];
#pragma unroll
    for (int mt = 0; mt < 2; mt++)
#pragma unroll
        for (int nt = 0; nt < 4; nt++) acc[mt][nt] = (f32x4){0.f, 0.f, 0.f, 0.f};

    for (int kb = 0; kb < CCH; kb += 64) {
        __syncthreads();
#pragma unroll
        for (int i = 0; i < 2; i++) {
            const int c = wave * 2 + i;
            const int row = c * 8 + sl;
            load_lds_16(Wb + (size_t)(mb * 64 + row) * CCH + kb + scol, &Asm[c * 512]);
        }
#pragma unroll
        for (int i = 0; i < 4; i++) {
            const int c = wave * 4 + i;
            const int row = c * 8 + sl;
            load_lds_16(xnT + (size_t)(nb * 128 + row) * CCH + kb + scol, &Bsm[c * 512]);
        }
        __syncthreads();
#pragma unroll
        for (int kk = 0; kk < 2; kk++) {
            const int so = ((kk * 4 + quad) ^ (l15 & 7)) << 3;
            short8 a[2], b[4];
#pragma unroll
            for (int mt = 0; mt < 2; mt++)
                a[mt] = *(const short8*)(Asm + (wm * 32 + mt * 16 + l15) * 64 + so);
#pragma unroll
            for (int nt = 0; nt < 4; nt++)
                b[nt] = *(const short8*)(Bsm + (wn * 64 + nt * 16 + l15) * 64 + so);
#pragma unroll
            for (int mt = 0; mt < 2; mt++)
#pragma unroll
                for (int nt = 0; nt < 4; nt++)
                    acc[mt][nt] = __builtin_amdgcn_mfma_f32_16x16x32_bf16(a[mt], b[nt], acc[mt][nt], 0, 0, 0);
        }
    }

    const int sel = mb >> 3;                 // 64-row blocks: 0..7=Q, 8..15=K, 16..23=V
#pragma unroll
    for (int mt = 0; mt < 2; mt++) {
        const int m0 = mb * 64 + wm * 32 + mt * 16 + quad * 4;
        float bs[4] = {bias[m0], bias[m0 + 1], bias[m0 + 2], bias[m0 + 3]};
        if (sel < 2) {
            unsigned short* dst = sel ? kt : qt;
            const float mul = sel ? 1.0f : QSCALE;
            const int h  = (m0 >> 6) & 7;
            const int d0 = m0 & 63;
#pragma unroll
            for (int nt = 0; nt < 4; nt++) {
                const int t = nb * 128 + wn * 64 + nt * 16 + l15;
                ushort4 o;
                o.x = f2bf((acc[mt][nt][0] + bs[0]) * mul);
                o.y = f2bf((acc[mt][nt][1] + bs[1]) * mul);
                o.z = f2bf((acc[mt][nt][2] + bs[2]) * mul);
                o.w = f2bf((acc[mt][nt][3] + bs[3]) * mul);
                *(ushort4*)(dst + ((size_t)h * SEQN + t) * HD + d0) = o;
            }
        } else {
            const int c0 = m0 - 1024;
#pragma unroll
            for (int nt = 0; nt < 4; nt++) {
                const int t = nb * 128 + wn * 64 + nt * 16 + l15;
#pragma unroll
                for (int reg = 0; reg < 4; reg++)
                    vv[(size_t)(c0 + reg) * SEQN + t] = f2bf(acc[mt][nt][reg] + bs[reg]);
            }
        }
    }
}

// ---------------- proj GEMM: 64x128 tile, BK=64, LDS-staged; +bias+resid fp32 out
__global__ __launch_bounds__(256) void gemm_proj(const unsigned short* __restrict__ Wb,
                                                 const unsigned short* __restrict__ attnoT,
                                                 const float* __restrict__ bias,
                                                 const float* __restrict__ resid,
                                                 float* __restrict__ out) {
    __shared__ __align__(16) unsigned short Asm[64 * 64];
    __shared__ __align__(16) unsigned short Bsm[128 * 64];
    const int tid = threadIdx.x;
    const int wave = tid >> 6;
    const int lane = tid & 63;
    const int quad = lane >> 4;
    const int l15  = lane & 15;
    const int wm = wave >> 1, wn = wave & 1;
    const int nb = blockIdx.x, mb = blockIdx.y;
    const int sl = lane >> 3, slot = lane & 7;
    const int scol = (slot ^ sl) * 8;

    f32x4 acc[2][4];
#pragma unroll
    for (int mt = 0; mt < 2; mt++)
#pragma unroll
        for (int nt = 0; nt < 4; nt++) acc[mt][nt] = (f32x4){0.f, 0.f, 0.f, 0.f};

    for (int kb = 0; kb < CCH; kb += 64) {
        __syncthreads();
#pragma unroll
        for (int i = 0; i < 2; i++) {
            const int c = wave * 2 + i;
            const int row = c * 8 + sl;
            load_lds_16(Wb + (size_t)(mb * 64 + row) * CCH + kb + scol, &Asm[c * 512]);
        }
#pragma unroll
        for (int i = 0; i < 4; i++) {
            const int c = wave * 4 + i;
            const int row = c * 8 + sl;
            load_lds_16(attnoT + (size_t)(nb * 128 + row) * CCH + kb + scol, &Bsm[c * 512]);
        }
        __syncthreads();
#pragma unroll
        for (int kk = 0; kk < 2; kk++) {
            const int so = ((kk * 4 + quad) ^ (l15 & 7)) << 3;
            short8 a[2], b[4];
#pragma unroll
            for (int mt = 0; mt < 2; mt++)
                a[mt] = *(const short8*)(Asm + (wm * 32 + mt * 16 + l15) * 64 + so);
#pragma unroll
            for (int nt = 0; nt < 4; nt++)
                b[nt] = *(const short8*)(Bsm + (wn * 64 + nt * 16 + l15) * 64 + so);
#pragma unroll
            for (int mt = 0; mt < 2; mt++)
#pragma unroll
                for (int nt = 0; nt < 4; nt++)
                    acc[mt][nt] = __builtin_amdgcn_mfma_f32_16x16x32_bf16(a[mt], b[nt], acc[mt][nt], 0, 0, 0);
        }
    }

#pragma unroll
    for (int mt = 0; mt < 2; mt++) {
        const int m0 = mb * 64 + wm * 32 + mt * 16 + quad * 4;
        float bs[4] = {bias[m0], bias[m0 + 1], bias[m0 + 2], bias[m0 + 3]};
#pragma unroll
        for (int nt = 0; nt < 4; nt++) {
            const int n = nb * 128 + wn * 64 + nt * 16 + l15;
#pragma unroll
            for (int reg = 0; reg < 4; reg++) {
                const size_t off = (size_t)(m0 + reg) * SEQN + n;
                out[off] = acc[mt][nt][reg] + bs[reg] + resid[off];
            }
        }
    }
}

// ---------------- Flash attention: 512-thread blocks, 8 waves = 2 s-halves x
// 4 t-quarters; per-wave tile stays 32s x 32t (96 VGPR, known no-spill).
// Each staged 64-s K/V tile now feeds 128 t -> staged traffic halves vs r9.
// Static softmax (exp2, scale in Q), P in registers (full-K=32 MFMA), dbuf
// LDS, XCD pin (h = bid & 7).
__global__ __launch_bounds__(512) void attn(const unsigned short* __restrict__ qt,
                                            const unsigned short* __restrict__ kt,
                                            const unsigned short* __restrict__ vv,
                                            unsigned short* __restrict__ po,
                                            float2* __restrict__ ml) {
    const int tid  = threadIdx.x;
    const int wave = tid >> 6;     // 0..7
    const int lane = tid & 63;
    const int quad = lane >> 4;
    const int l15  = lane & 15;
    const int ws = wave >> 2;      // s-half owner (32 s)
    const int wt = wave & 3;       // t-quarter owner (32 t)
    // XCD-aware decode: round-robin dispatch puts bid%8 on XCD bid%8.
    const int bid = blockIdx.x;
    const int h   = bid & 7;
    const int r   = bid >> 3;      // 0..127 = 32 tb x 4 cb
    const int cb  = r >> 5;
    const int tb  = (r & 31) * 128;

    const unsigned short* qh = qt + (size_t)h * SEQN * HD;
    const unsigned short* kh = kt + (size_t)h * SEQN * HD;
    const unsigned short* vh = vv + (size_t)h * HD * SEQN;

    // kv[buf][0..4095] = K tile (64 s x 64 d, swizzled); [4096..8191] = V (64 d x 64 s)
    __shared__ __align__(16) unsigned short kv[2][8192];
    __shared__ float lredm[8][2][16];

    const int sl = lane >> 3, slot = lane & 7;
    const int scol = (slot ^ sl) * 8;
    const int x7 = l15 & 7;

    // hoisted LDS element offsets
    int kaoff[2][2];
#pragma unroll
    for (int sm = 0; sm < 2; sm++)
#pragma unroll
        for (int k = 0; k < 2; k++)
            kaoff[sm][k] = (ws * 32 + sm * 16 + l15) * 64 + (((k * 4 + quad) ^ x7) << 3);
    int vpoff[4][2];
#pragma unroll
    for (int dt = 0; dt < 4; dt++)
#pragma unroll
        for (int sm = 0; sm < 2; sm++)
            vpoff[dt][sm] = 4096 + (dt * 16 + l15) * 64 +
                            (((ws * 4 + sm * 2 + (quad >> 1)) ^ x7) << 3) + ((quad & 1) << 2);

    // Q B-frags persistent: B[k=d][n=t] for this wave's 2 t-tiles
    short8 qf[2][2];
#pragma unroll
    for (int nt = 0; nt < 2; nt++) {
        const unsigned short* qp = qh + (size_t)(tb + wt * 32 + nt * 16 + l15) * HD + quad * 8;
        qf[nt][0] = *(const short8*)(qp);
        qf[nt][1] = *(const short8*)(qp + 32);
    }

    f32x4 oacc[4][2];   // [d-tile 0..3][t-tile 0..1], this wave's s-half partial
#pragma unroll
    for (int dt = 0; dt < 4; dt++)
#pragma unroll
        for (int nt = 0; nt < 2; nt++) oacc[dt][nt] = (f32x4){0.f, 0.f, 0.f, 0.f};
    float lsum[2] = {0.f, 0.f};

    const int s_beg = cb * CHUNK;
    const int NIT = CHUNK / 64;

    // running global staging pointers: wave stages K chunk `wave` + V chunk `wave`
    const unsigned short* kgp = kh + (size_t)(s_beg + wave * 8 + sl) * HD + scol;
    const unsigned short* vgp = vh + (size_t)(wave * 8 + sl) * SEQN + s_beg + scol;

    // prologue: stage chunk 0 into buf 0
    load_lds_16(kgp, &kv[0][wave * 512]);
    load_lds_16(vgp, &kv[0][4096 + wave * 512]);
    kgp += 64 * HD; vgp += 64;

    auto compute = [&](const unsigned short* ksb) {
        // ---- S^T = K·Q^T over this wave's 32 s-rows, 32 t-cols
        short8 ka[2][2];
#pragma unroll
        for (int sm = 0; sm < 2; sm++) {
            ka[sm][0] = *(const short8*)(ksb + kaoff[sm][0]);
            ka[sm][1] = *(const short8*)(ksb + kaoff[sm][1]);
        }
        f32x4 sacc[2][2];
#pragma unroll
        for (int sm = 0; sm < 2; sm++)
#pragma unroll
            for (int nt = 0; nt < 2; nt++) {
                f32x4 z = (f32x4){0.f, 0.f, 0.f, 0.f};
                z = __builtin_amdgcn_mfma_f32_16x16x32_bf16(ka[sm][0], qf[nt][0], z, 0, 0, 0);
                sacc[sm][nt] = __builtin_amdgcn_mfma_f32_16x16x32_bf16(ka[sm][1], qf[nt][1], z, 0, 0, 0);
            }

        // ---- static softmax + pack BOTH s-subtiles into ONE full-K B-frag
        short8 pfull[2];
#pragma unroll
        for (int nt = 0; nt < 2; nt++) {
            float a0 = EXP2(sacc[0][nt][0]);
            float a1 = EXP2(sacc[0][nt][1]);
            float a2 = EXP2(sacc[0][nt][2]);
            float a3 = EXP2(sacc[0][nt][3]);
            float b0 = EXP2(sacc[1][nt][0]);
            float b1 = EXP2(sacc[1][nt][1]);
            float b2 = EXP2(sacc[1][nt][2]);
            float b3 = EXP2(sacc[1][nt][3]);
            lsum[nt] += ((a0 + a1) + (a2 + a3)) + ((b0 + b1) + (b2 + b3));
            pfull[nt] = frag4(pkbf(a0, a1), pkbf(a2, a3), pkbf(b0, b1), pkbf(b2, b3));
        }

        // ---- O^T += V^T·P^T, full K=32
#pragma unroll
        for (int dt = 0; dt < 4; dt++) {
            uint2 v0 = *(const uint2*)(ksb + vpoff[dt][0]);
            uint2 v1 = *(const uint2*)(ksb + vpoff[dt][1]);
            short8 va = frag4(v0.x, v0.y, v1.x, v1.y);
#pragma unroll
            for (int nt = 0; nt < 2; nt++)
                oacc[dt][nt] = __builtin_amdgcn_mfma_f32_16x16x32_bf16(va, pfull[nt], oacc[dt][nt], 0, 0, 0);
        }
    };

    for (int it2 = 0; it2 < NIT / 2; it2++) {
        // even iter: compute buf0, stage into buf1
        __syncthreads();
        load_lds_16(kgp, &kv[1][wave * 512]);
        load_lds_16(vgp, &kv[1][4096 + wave * 512]);
        kgp += 64 * HD; vgp += 64;
        compute(&kv[0][0]);
        // odd iter: compute buf1, stage into buf0 (except last)
        __syncthreads();
        if (it2 + 1 < NIT / 2) {
            load_lds_16(kgp, &kv[0][wave * 512]);
            load_lds_16(vgp, &kv[0][4096 + wave * 512]);
            kgp += 64 * HD; vgp += 64;
        }
        compute(&kv[1][0]);
    }

    // ---- cross-wave (s-half pair) reduction through LDS
    __syncthreads();
    unsigned int* exg = (unsigned int*)&kv[0][0];   // 32 tiles x 64 lanes x 2 dw = 16 KB
#pragma unroll
    for (int nt = 0; nt < 2; nt++) {
        lsum[nt] += __shfl_xor(lsum[nt], 16);
        lsum[nt] += __shfl_xor(lsum[nt], 32);
    }
    if (quad == 0) {
        lredm[wave][0][l15] = lsum[0];
        lredm[wave][1][l15] = lsum[1];
    }
#pragma unroll
    for (int j = 0; j < 2; j++) {
        const int dt = (ws ^ 1) * 2 + j;      // the d-half I do NOT own
#pragma unroll
        for (int nt = 0; nt < 2; nt++) {
            const int idx = (((wave * 2 + j) * 2 + nt) * 64 + lane) * 2;
            exg[idx]     = pkbf(oacc[dt][nt][0], oacc[dt][nt][1]);
            exg[idx + 1] = pkbf(oacc[dt][nt][2], oacc[dt][nt][3]);
        }
    }
    __syncthreads();
    const int pw = wave ^ 4;                  // partner: other s-half, same t-quarter
    float lt[2];
#pragma unroll
    for (int nt = 0; nt < 2; nt++)
        lt[nt] = lredm[wave][nt][l15] + lredm[pw][nt][l15];

#pragma unroll
    for (int j = 0; j < 2; j++) {
        const int dtm = ws * 2 + j;           // my owned d-tiles
#pragma unroll
        for (int nt = 0; nt < 2; nt++) {
            const int idx = (((pw * 2 + j) * 2 + nt) * 64 + lane) * 2;
            unsigned int r0 = exg[idx], r1 = exg[idx + 1];
            f32x4 o = oacc[dtm][nt];
            o[0] += lo_f(r0); o[1] += hi_f(r0);
            o[2] += lo_f(r1); o[3] += hi_f(r1);
            const float rl = 1.0f / lt[nt];
            const int t = tb + wt * 32 + nt * 16 + l15;
            ushort4 ov;
            ov.x = f2bf(o[0] * rl); ov.y = f2bf(o[1] * rl);
            ov.z = f2bf(o[2] * rl); ov.w = f2bf(o[3] * rl);
            *(ushort4*)(po + ((size_t)(cb * NH + h) * SEQN + t) * HD + dtm * 16 + quad * 4) = ov;
            if (ws == 0 && quad == 0 && j == 0)
                ml[(size_t)(cb * NH + h) * SEQN + t] = make_float2(0.f, lt[nt]);
        }
    }
}

// ---------------- merge s-chunks (weights = per-chunk l) -> attnoT [t][c] bf16
__global__ __launch_bounds__(256) void attn_merge(const unsigned short* __restrict__ po,
                                                  const float2* __restrict__ ml,
                                                  unsigned short* __restrict__ attnoT) {
    const int idx = blockIdx.x * 256 + threadIdx.x;
    const int t  = idx >> 7;
    const int c4 = (idx & 127) << 2;
    const int h  = c4 >> 6;
    const int d  = c4 & 63;

    float a0 = 0.f, a1 = 0.f, a2 = 0.f, a3 = 0.f, denom = 0.f;
#pragma unroll
    for (int cb = 0; cb < SC; cb++) {
        float wgt = ml[(size_t)(cb * NH + h) * SEQN + t].y;
        denom += wgt;
        ushort4 o = *(const ushort4*)(po + ((size_t)(cb * NH + h) * SEQN + t) * HD + d);
        a0 += wgt * bf2f(o.x);
        a1 += wgt * bf2f(o.y);
        a2 += wgt * bf2f(o.z);
        a3 += wgt * bf2f(o.w);
    }
    const float rd = 1.0f / denom;
    ushort4 r;
    r.x = f2bf(a0 * rd); r.y = f2bf(a1 * rd); r.z = f2bf(a2 * rd); r.w = f2bf(a3 * rd);
    *(ushort4*)(attnoT + (size_t)t * CCH + c4) = r;
}

extern "C" void kernel_launch(void* const* d_in, const int* in_sizes, int n_in,
                              void* d_out, int out_size, void* d_ws, size_t ws_size,
                              hipStream_t stream) {
    const float* x      = (const float*)d_in[0];
    const float* gn_w   = (const float*)d_in[1];
    const float* gn_b   = (const float*)d_in[2];
    const float* qkv_w  = (const float*)d_in[3];
    const float* qkv_b  = (const float*)d_in[4];
    const float* proj_w = (const float*)d_in[5];
    const float* proj_b = (const float*)d_in[6];
    float* out = (float*)d_out;

    char* ws = (char*)d_ws;
    float2* partials = (float2*)ws;                                // 2 KB
    unsigned short* xnT   = (unsigned short*)(ws + 2048);          // 4096*512
    unsigned short* wq_bf = xnT + (size_t)SEQN * CCH;              // 1536*512
    unsigned short* wp_bf = wq_bf + (size_t)3 * CCH * CCH;         // 512*512
    unsigned short* qt    = wp_bf + (size_t)CCH * CCH;             // 8*4096*64
    unsigned short* kt    = qt + (size_t)NH * SEQN * HD;
    unsigned short* vv    = kt + (size_t)NH * SEQN * HD;
    unsigned short* po    = vv + (size_t)NH * SEQN * HD;           // SC*8*4096*64
    unsigned short* attnoT = po + (size_t)SC * NH * SEQN * HD;     // 4096*512
    float2* ml = (float2*)(attnoT + (size_t)SEQN * CCH);           // SC*8*4096

    prep<<<256 + (3 * CCH * CCH + CCH * CCH) / 4 / 256, 256, 0, stream>>>(
        x, partials, qkv_w, proj_w, wq_bf, wp_bf);
    gn_norm_t<<<dim3(SEQN / 64, CCH / 64), 256, 0, stream>>>(x, partials, gn_w, gn_b, xnT);
    gemm_qkv<<<dim3(SEQN / 128, 3 * CCH / 64), 256, 0, stream>>>(wq_bf, xnT, qkv_b, qt, kt, vv);
    attn<<<(SEQN / 128) * SC * NH, 512, 0, stream>>>(qt, kt, vv, po, ml);
    attn_merge<<<SEQN * 128 / 256, 256, 0, stream>>>(po, ml, attnoT);
    gemm_proj<<<dim3(SEQN / 128, CCH / 64), 256, 0, stream>>>(wp_bf, attnoT, proj_b, x, out);
}